// Round 10
// baseline (402.536 us; speedup 1.0000x reference)
//
#include <hip/hip_runtime.h>
#include <stdint.h>

#define B_  2
#define T_  2048
#define D_  1024
#define H_  4
#define S_  64
#define W_  512
#define CK_ 256
#define NC_ 32      // T_/64 chunks

typedef __attribute__((ext_vector_type(8))) short bf16x8;
typedef __attribute__((ext_vector_type(4))) float f32x4;
typedef __attribute__((ext_vector_type(4))) unsigned short u16x4;

__device__ __forceinline__ float bf2f(unsigned short u){ return __uint_as_float(((unsigned int)u)<<16); }
__device__ __forceinline__ unsigned short f2bf(float f){
  unsigned int u = __float_as_uint(f);
  u += 0x7fffu + ((u>>16)&1u);
  return (unsigned short)(u>>16);
}
__device__ __forceinline__ void split2(float y, unsigned short& hi, unsigned short& lo){
  hi = f2bf(y);
  lo = f2bf(y - bf2f(hi));
}

// async global->LDS, 16B per lane; lds base must be wave-uniform (HW adds lane*16)
__device__ __forceinline__ void gl_lds16(const unsigned short* g, unsigned short* l){
  __builtin_amdgcn_global_load_lds(
      (const __attribute__((address_space(1))) unsigned int*)g,
      (__attribute__((address_space(3))) unsigned int*)l, 16, 0, 0);
}

// ---------------- RMSNorm: x(B*T,D) -> split bf16 hi/lo ----------------
__global__ void rmsnorm_split_kernel(const float* __restrict__ x, const float* __restrict__ w,
                                     unsigned short* __restrict__ ohi, unsigned short* __restrict__ olo){
  int row = blockIdx.x, tid = threadIdx.x;
  const float* xr = x + (size_t)row*D_;
  float v0=xr[tid], v1=xr[tid+256], v2=xr[tid+512], v3=xr[tid+768];
  __shared__ float red[256];
  red[tid] = v0*v0+v1*v1+v2*v2+v3*v3;
  __syncthreads();
  for(int s=128;s>0;s>>=1){ if(tid<s) red[tid]+=red[tid+s]; __syncthreads(); }
  float r = rsqrtf(red[0]/(float)D_ + 1e-5f);
  size_t base = (size_t)row*D_;
  float y0=v0*r*w[tid], y1=v1*r*w[tid+256], y2=v2*r*w[tid+512], y3=v3*r*w[tid+768];
  unsigned short hh, ll;
  split2(y0,hh,ll); ohi[base+tid]=hh;     olo[base+tid]=ll;
  split2(y1,hh,ll); ohi[base+tid+256]=hh; olo[base+tid+256]=ll;
  split2(y2,hh,ll); ohi[base+tid+512]=hh; olo[base+tid+512]=ll;
  split2(y3,hh,ll); ohi[base+tid+768]=hh; olo[base+tid+768]=ll;
}

// ---------------- weight concat + split: rows [Wq;Wk;Ws;Wv;Wg;Wo] ----------------
__global__ void wsplit_kernel(const float* __restrict__ Wq, const float* __restrict__ Wk,
                              const float* __restrict__ Ws, const float* __restrict__ Wv,
                              const float* __restrict__ Wg, const float* __restrict__ Wo,
                              unsigned short* __restrict__ whi, unsigned short* __restrict__ wlo){
  int row = blockIdx.x, tid = threadIdx.x;
  const float* src;
  if(row < 1024)      src = Wq + (size_t)row*1024;
  else if(row < 2048) src = Wk + (size_t)(row-1024)*1024;
  else if(row < 3072) src = Ws + (size_t)(row-2048)*1024;
  else if(row < 4096) src = Wv + (size_t)(row-3072)*1024;
  else if(row < 4352) src = Wg + (size_t)(row-4096)*1024;
  else                src = Wo + (size_t)(row-4352)*1024;
  f32x4 vv = *(const f32x4*)(src + tid*4);
  u16x4 hh, ll;
  #pragma unroll
  for(int j=0;j<4;j++){ unsigned short a,b; split2(vv[j],a,b); hh[j]=a; ll[j]=b; }
  *(u16x4*)(whi + (size_t)row*1024 + tid*4) = hh;
  *(u16x4*)(wlo + (size_t)row*1024 + tid*4) = ll;
}

// ---------------- split-bf16 MFMA GEMM: C[M,4352] = A[4096,1024] * Wcat^T ----------------
// mode 0: fused epilogue -> qks(bf16), vt/vtlo(bf16 hi/lo transposed), g(f32)
// mode 1: Cf[row*1024+col] = val (Wo projection), chunked XCD swizzle.
// 128x128 tile, BK=64 (full-cacheline DMA), 4 waves (2x2), each wave 64x64.
// Staging via global_load_lds; XOR-16B-chunk swizzle on BOTH DMA source and ds_read.
__global__ __launch_bounds__(256,2) void gemm_bf16s(
    const unsigned short* __restrict__ Ahi, const unsigned short* __restrict__ Alo,
    const unsigned short* __restrict__ Whi, const unsigned short* __restrict__ Wlo,
    unsigned short* __restrict__ qks, unsigned short* __restrict__ vt,
    unsigned short* __restrict__ vtlo, float* __restrict__ gout,
    float* __restrict__ Cf, int mode)
{
  __shared__ unsigned short Ah_s[128*64];
  __shared__ unsigned short Al_s[128*64];
  __shared__ unsigned short Bh_s[128*64];
  __shared__ unsigned short Bl_s[128*64];
  int tid = threadIdx.x;
  int lane = tid & 63, w = tid >> 6;
  int quad = lane >> 4, lq = lane & 15;
  int wr = w >> 1, wc = w & 1;
  int bid = blockIdx.y*gridDim.x + blockIdx.x;
  int row0, col0;
  if(mode == 0){
    // bijective: 8 XCD x 136 slots = (rx 4, cx 2) x (sr 8, sc 17) = 32 x 34 tiles
    int xcd = bid & 7, slot = bid >> 3;
    int rx = xcd & 3, cx = xcd >> 2;
    int sr = slot / 17, sc2 = slot % 17;
    row0 = (rx*8 + sr)*128;
    col0 = (cx*17 + sc2)*128;
  } else {
    int q8 = (gridDim.x*gridDim.y) >> 3;
    int wg = (bid & 7)*q8 + (bid >> 3);
    col0 = (wg % gridDim.x)*128;
    row0 = (wg / gridDim.x)*128;
  }

  int l8 = lane >> 3;            // 0..7: row within an 8-row DMA slab
  int chk = lane & 7;            // 16B chunk within the 128B row

  f32x4 acc[4][4];
  #pragma unroll
  for(int i=0;i<4;i++)
    #pragma unroll
    for(int j=0;j<4;j++) acc[i][j] = (f32x4){0.f,0.f,0.f,0.f};

  for(int kt=0; kt<1024; kt+=64){
    __syncthreads();   // all waves done reading previous tile
    #pragma unroll
    for(int j=0;j<4;j++){
      int rl = w*32 + j*8 + l8;                 // per-lane row 0..127
      int sc = (chk ^ (rl & 7))*8;              // swizzled source chunk (shorts)
      int lbase = (w*32 + j*8)*64;              // wave-uniform LDS base (shorts)
      gl_lds16(Ahi + (size_t)(row0+rl)*1024 + kt + sc, Ah_s + lbase);
      gl_lds16(Alo + (size_t)(row0+rl)*1024 + kt + sc, Al_s + lbase);
      gl_lds16(Whi + (size_t)(col0+rl)*1024 + kt + sc, Bh_s + lbase);
      gl_lds16(Wlo + (size_t)(col0+rl)*1024 + kt + sc, Bl_s + lbase);
    }
    __syncthreads();   // vmcnt drain: LDS tile ready
    #pragma unroll
    for(int ks=0;ks<2;ks++){
      bf16x8 afh[4], afl[4], bfh[4], bfl[4];
      #pragma unroll
      for(int i=0;i<4;i++){
        int Ra = wr*64+i*16+lq;
        int ca = ((ks*4+quad) ^ (Ra&7))*8;
        afh[i] = *(const bf16x8*)(const void*)(Ah_s + Ra*64 + ca);
        afl[i] = *(const bf16x8*)(const void*)(Al_s + Ra*64 + ca);
        int Rb = wc*64+i*16+lq;
        int cb = ((ks*4+quad) ^ (Rb&7))*8;
        bfh[i] = *(const bf16x8*)(const void*)(Bh_s + Rb*64 + cb);
        bfl[i] = *(const bf16x8*)(const void*)(Bl_s + Rb*64 + cb);
      }
      #pragma unroll
      for(int mi=0;mi<4;mi++)
        #pragma unroll
        for(int ni=0;ni<4;ni++){
          acc[mi][ni] = __builtin_amdgcn_mfma_f32_16x16x32_bf16(afh[mi], bfh[ni], acc[mi][ni], 0,0,0);
          acc[mi][ni] = __builtin_amdgcn_mfma_f32_16x16x32_bf16(afh[mi], bfl[ni], acc[mi][ni], 0,0,0);
          acc[mi][ni] = __builtin_amdgcn_mfma_f32_16x16x32_bf16(afl[mi], bfh[ni], acc[mi][ni], 0,0,0);
        }
    }
  }

  int rbase = row0 + wr*64, cbase = col0 + wc*64;
  if(mode == 1){
    #pragma unroll
    for(int mi=0;mi<4;mi++)
      #pragma unroll
      for(int ni=0;ni<4;ni++)
        #pragma unroll
        for(int i=0;i<4;i++)
          Cf[(size_t)(rbase+mi*16+quad*4+i)*1024 + cbase+ni*16+lq] = acc[mi][ni][i];
  } else if(col0 < 3072){
    unsigned short* dst = qks + (size_t)(col0>>10)*4194304;
    #pragma unroll
    for(int mi=0;mi<4;mi++)
      #pragma unroll
      for(int ni=0;ni<4;ni++)
        #pragma unroll
        for(int i=0;i<4;i++){
          int rr = rbase+mi*16+quad*4+i, cc = (cbase+ni*16+lq) & 1023;
          dst[(size_t)rr*1024 + cc] = f2bf(acc[mi][ni][i]);
        }
  } else if(col0 < 4096){
    #pragma unroll
    for(int mi=0;mi<4;mi++)
      #pragma unroll
      for(int ni=0;ni<4;ni++)
        #pragma unroll
        for(int i=0;i<4;i++){
          int rr = rbase+mi*16+quad*4+i, cl = (cbase+ni*16+lq) & 1023;
          unsigned short hh2, ll2;
          split2(acc[mi][ni][i], hh2, ll2);
          int hh = cl>>8, cv = cl&255, bb = rr>>11, tt = rr&2047;
          size_t ti = ((size_t)((bb*H_+hh)*256 + cv))*T_ + tt;
          vt[ti] = hh2;
          vtlo[ti] = ll2;
        }
  } else {
    #pragma unroll
    for(int mi=0;mi<4;mi++)
      #pragma unroll
      for(int ni=0;ni<4;ni++)
        #pragma unroll
        for(int i=0;i<4;i++){
          int rr = rbase+mi*16+quad*4+i, cl = cbase+ni*16+lq - 4096;
          gout[(size_t)rr*256 + cl] = acc[mi][ni][i];
        }
  }
}

// ---------------- softmax over 256 (in place), one row per block ----------------
__global__ void softmax256_kernel(float* __restrict__ g){
  int row = blockIdx.x, tid = threadIdx.x;
  float x = g[(size_t)row*256+tid];
  __shared__ float red[256];
  red[tid]=x; __syncthreads();
  for(int s=128;s>0;s>>=1){ if(tid<s) red[tid]=fmaxf(red[tid],red[tid+s]); __syncthreads(); }
  float m = red[0]; __syncthreads();
  float e = expf(x-m);
  red[tid]=e; __syncthreads();
  for(int s=128;s>0;s>>=1){ if(tid<s) red[tid]+=red[tid+s]; __syncthreads(); }
  g[(size_t)row*256+tid] = e/red[0];
}

// ---------------- chunk outer (S path): out[s][c] = sum_u G[u,s]*S[u,c] ----------------
__global__ __launch_bounds__(256,1) void chunk_outer_mfma(
    const unsigned short* __restrict__ gthi, const unsigned short* __restrict__ gtlo,
    const unsigned short* __restrict__ s_bf, float* __restrict__ out)
{
  __shared__ unsigned short xh_lds[256*72];
  int n=blockIdx.x, h=blockIdx.y, b=blockIdx.z;
  int tid=threadIdx.x, lane=tid&63, w=tid>>6;
  int quad=lane>>4, lq=lane&15;
  int t0=n*64, bh=b*H_+h;

  const unsigned short* sb = s_bf + (size_t)(b*T_+t0)*D_ + h*CK_ + tid;
  for(int p2=0;p2<8;p2++){
    union{ unsigned short u[8]; bf16x8 v8; } r8;
    #pragma unroll
    for(int j=0;j<8;j++)
      r8.u[j] = sb[(size_t)(p2*8+j)*D_];
    *(bf16x8*)(void*)&xh_lds[tid*72 + p2*8] = r8.v8;
  }
  __syncthreads();

  size_t gtbase = ((size_t)bh*NC_ + n)*64;
  f32x4 acc[4][4];
  #pragma unroll
  for(int i=0;i<4;i++)
    #pragma unroll
    for(int j=0;j<4;j++) acc[i][j] = (f32x4){0.f,0.f,0.f,0.f};

  #pragma unroll
  for(int ks=0; ks<2; ks++){
    bf16x8 ah[4], al[4], bh4[4];
    #pragma unroll
    for(int mi=0;mi<4;mi++){
      ah[mi] = *(const bf16x8*)(const void*)(gthi + (gtbase + mi*16+lq)*64 + ks*32 + quad*8);
      al[mi] = *(const bf16x8*)(const void*)(gtlo + (gtbase + mi*16+lq)*64 + ks*32 + quad*8);
    }
    #pragma unroll
    for(int ni=0;ni<4;ni++)
      bh4[ni] = *(const bf16x8*)(const void*)&xh_lds[(w*64+ni*16+lq)*72 + ks*32 + quad*8];
    #pragma unroll
    for(int mi=0;mi<4;mi++)
      #pragma unroll
      for(int ni=0;ni<4;ni++){
        acc[mi][ni] = __builtin_amdgcn_mfma_f32_16x16x32_bf16(ah[mi], bh4[ni], acc[mi][ni], 0,0,0);
        acc[mi][ni] = __builtin_amdgcn_mfma_f32_16x16x32_bf16(al[mi], bh4[ni], acc[mi][ni], 0,0,0);
      }
  }
  size_t obase = ((size_t)bh*NC_ + n)*16384;
  #pragma unroll
  for(int mi=0;mi<4;mi++)
    #pragma unroll
    for(int ni=0;ni<4;ni++)
      #pragma unroll
      for(int i=0;i<4;i++){
        int s = mi*16 + quad*4 + i, c = w*64 + ni*16 + lq;
        out[obase + (size_t)s*256 + c] = acc[mi][ni][i];
      }
}

// ---------------- chunk outer (V path): out[c][s] = sum_u G[u,s]*V[u,c] ----------------
__global__ __launch_bounds__(256,1) void chunk_outer_vt(
    const unsigned short* __restrict__ gthi, const unsigned short* __restrict__ gtlo,
    const unsigned short* __restrict__ vt, const unsigned short* __restrict__ vtlo,
    float* __restrict__ out)
{
  int n=blockIdx.x, h=blockIdx.y, b=blockIdx.z;
  int tid=threadIdx.x, lane=tid&63, w=tid>>6;
  int quad=lane>>4, lq=lane&15;
  int t0=n*64, bh=b*H_+h;
  size_t gtbase = ((size_t)bh*NC_ + n)*64;
  f32x4 acc[4][4];
  #pragma unroll
  for(int i=0;i<4;i++)
    #pragma unroll
    for(int j=0;j<4;j++) acc[i][j] = (f32x4){0.f,0.f,0.f,0.f};

  #pragma unroll
  for(int ks=0; ks<2; ks++){
    bf16x8 ah[4], al[4];
    #pragma unroll
    for(int mi=0;mi<4;mi++){
      ah[mi] = *(const bf16x8*)(const void*)(gthi + (gtbase + mi*16+lq)*64 + ks*32 + quad*8);
      al[mi] = *(const bf16x8*)(const void*)(gtlo + (gtbase + mi*16+lq)*64 + ks*32 + quad*8);
    }
    #pragma unroll
    for(int ni=0;ni<4;ni++){
      size_t vo = ((size_t)(bh*256 + w*64 + ni*16 + lq))*T_ + t0 + ks*32 + quad*8;
      bf16x8 vh = *(const bf16x8*)(const void*)(vt + vo);
      bf16x8 vl = *(const bf16x8*)(const void*)(vtlo + vo);
      #pragma unroll
      for(int mi=0;mi<4;mi++){
        acc[mi][ni] = __builtin_amdgcn_mfma_f32_16x16x32_bf16(ah[mi], vh, acc[mi][ni], 0,0,0);
        acc[mi][ni] = __builtin_amdgcn_mfma_f32_16x16x32_bf16(al[mi], vh, acc[mi][ni], 0,0,0);
        acc[mi][ni] = __builtin_amdgcn_mfma_f32_16x16x32_bf16(ah[mi], vl, acc[mi][ni], 0,0,0);
      }
    }
  }
  size_t obase = ((size_t)bh*NC_ + n)*16384;
  #pragma unroll
  for(int mi=0;mi<4;mi++)
    #pragma unroll
    for(int ni=0;ni<4;ni++){
      int c = w*64 + ni*16 + lq, s0 = mi*16 + quad*4;
      *(f32x4*)&out[obase + (size_t)c*64 + s0] = acc[mi][ni];
    }
}

// ---------------- exclusive prefix over chunks -> split bf16 hi/lo ----------------
__global__ void chunk_prefix_split_kernel(const float* __restrict__ arr,
    unsigned short* __restrict__ hi, unsigned short* __restrict__ lo){
  int idx = blockIdx.x*256 + threadIdx.x;
  int bh = idx >> 14, e = idx & 16383;
  float run = 0.f;
  size_t base = (size_t)bh*NC_*16384 + e;
  for(int n=0;n<NC_;n++){
    size_t a = base + (size_t)n*16384;
    float t = arr[a];
    unsigned short hh, ll;
    split2(run, hh, ll);
    hi[a] = hh; lo[a] = ll;
    run += t;
  }
}

// ---------------- g (B*T,256) -> GT[bh*NC+n][s][u] split bf16 hi/lo ----------------
__global__ __launch_bounds__(256) void g_transpose_split_kernel(const float* __restrict__ g,
    unsigned short* __restrict__ gthi, unsigned short* __restrict__ gtlo){
  int n=blockIdx.x, h=blockIdx.y, b=blockIdx.z;
  int tid=threadIdx.x, t0=n*64;
  __shared__ float tt[64][65];
  #pragma unroll
  for(int p=0;p<16;p++){
    int u = (tid>>6) + p*4, s = tid&63;
    tt[s][u] = g[((size_t)(b*T_ + t0 + u))*256 + h*64 + s];
  }
  __syncthreads();
  size_t base = ((size_t)(b*H_+h)*NC_ + n)*64;
  #pragma unroll
  for(int p=0;p<16;p++){
    int s = (tid>>6) + p*4, u = tid&63;
    unsigned short hh, ll;
    split2(tt[s][u], hh, ll);
    gthi[(base+s)*64 + u] = hh;
    gtlo[(base+s)*64 + u] = ll;
  }
}

// ---------------- sc_state via MFMA, 32-row half-chunk blocks (grid 64x4x2) ----------------
// Waves: (strip16 = (w&1)*16 rows of the 32) x (nsel = w>>1 half of u/s cols).
__global__ __launch_bounds__(256,2) void sc_state_mfma(
    const unsigned short* __restrict__ q_bf,
    const unsigned short* __restrict__ s_bf,
    const unsigned short* __restrict__ S1hi, const unsigned short* __restrict__ S1lo,
    const unsigned short* __restrict__ gthi, const unsigned short* __restrict__ gtlo,
    float* __restrict__ sc_state)
{
  int bx=blockIdx.x, h=blockIdx.y, b=blockIdx.z;
  int nt=bx>>1, half=bx&1;
  int tid=threadIdx.x, lane=tid&63, w=tid>>6;
  int quad=lane>>4, lq=lane&15;
  int t0c=nt*64, t0h=t0c+half*32, bh=b*H_+h;
  int strip16=(w&1)*16, nsel=w>>1;

  __shared__ unsigned short A_hi[32*72];
  __shared__ unsigned short A_lo[32*72];

  bf16x8 qf[8];
  const unsigned short* qrow = q_bf + ((size_t)(b*T_ + t0h + strip16 + lq))*D_ + h*CK_ + quad*8;
  #pragma unroll
  for(int ks=0;ks<8;ks++) qf[ks] = *(const bf16x8*)(const void*)(qrow + ks*32);

  // ---- stage 1: A = tril(Q S^T); this wave: strip16 rows x its 32 u-cols ----
  const unsigned short* sbase = s_bf + ((size_t)(b*T_ + t0c))*D_ + h*CK_;
  f32x4 a1[2];
  #pragma unroll
  for(int nf2=0;nf2<2;nf2++) a1[nf2] = (f32x4){0.f,0.f,0.f,0.f};
  #pragma unroll
  for(int ks=0;ks<8;ks++){
    #pragma unroll
    for(int nf2=0;nf2<2;nf2++){
      int nf = nsel*2 + nf2;
      bf16x8 sf = *(const bf16x8*)(const void*)(sbase + (size_t)(nf*16+lq)*D_ + ks*32 + quad*8);
      a1[nf2] = __builtin_amdgcn_mfma_f32_16x16x32_bf16(qf[ks], sf, a1[nf2], 0,0,0);
    }
  }
  #pragma unroll
  for(int nf2=0;nf2<2;nf2++){
    int u = (nsel*2+nf2)*16 + lq;
    #pragma unroll
    for(int i=0;i<4;i++){
      int lr = strip16 + quad*4 + i;        // 0..31 local
      int trow = half*32 + lr;              // chunk-local 0..63
      float val = (u <= trow) ? a1[nf2][i] : 0.f;
      unsigned short hh, ll;
      split2(val, hh, ll);
      A_hi[lr*72 + u] = hh;
      A_lo[lr*72 + u] = ll;
    }
  }
  __syncthreads();

  bf16x8 afh[2], afl[2];
  #pragma unroll
  for(int ks=0;ks<2;ks++){
    afh[ks] = *(const bf16x8*)(const void*)&A_hi[(strip16+lq)*72 + ks*32 + quad*8];
    afl[ks] = *(const bf16x8*)(const void*)&A_lo[(strip16+lq)*72 + ks*32 + quad*8];
  }

  // ---- stage 2: acc = Q@(S1hi+S1lo) + Ahi@(Ghi+Glo) + Alo@Ghi ----
  size_t s1base = ((size_t)bh*NC_ + nt)*16384;
  size_t gtbase = ((size_t)bh*NC_ + nt)*64;
  f32x4 acc2[2];
  #pragma unroll
  for(int nf2=0;nf2<2;nf2++) acc2[nf2] = (f32x4){0.f,0.f,0.f,0.f};
  #pragma unroll
  for(int ks=0;ks<8;ks++){
    #pragma unroll
    for(int nf2=0;nf2<2;nf2++){
      int nf = nsel*2 + nf2;
      size_t off = s1base + (size_t)(nf*16+lq)*256 + ks*32 + quad*8;
      bf16x8 b1 = *(const bf16x8*)(const void*)(S1hi + off);
      acc2[nf2] = __builtin_amdgcn_mfma_f32_16x16x32_bf16(qf[ks], b1, acc2[nf2], 0,0,0);
      bf16x8 b2 = *(const bf16x8*)(const void*)(S1lo + off);
      acc2[nf2] = __builtin_amdgcn_mfma_f32_16x16x32_bf16(qf[ks], b2, acc2[nf2], 0,0,0);
    }
  }
  #pragma unroll
  for(int ks=0;ks<2;ks++){
    #pragma unroll
    for(int nf2=0;nf2<2;nf2++){
      int nf = nsel*2 + nf2;
      size_t off = (gtbase + nf*16+lq)*64 + ks*32 + quad*8;
      bf16x8 gh = *(const bf16x8*)(const void*)(gthi + off);
      bf16x8 gl = *(const bf16x8*)(const void*)(gtlo + off);
      acc2[nf2] = __builtin_amdgcn_mfma_f32_16x16x32_bf16(afh[ks], gh, acc2[nf2], 0,0,0);
      acc2[nf2] = __builtin_amdgcn_mfma_f32_16x16x32_bf16(afh[ks], gl, acc2[nf2], 0,0,0);
      acc2[nf2] = __builtin_amdgcn_mfma_f32_16x16x32_bf16(afl[ks], gh, acc2[nf2], 0,0,0);
    }
  }
  #pragma unroll
  for(int nf2=0;nf2<2;nf2++){
    int nf = nsel*2 + nf2;
    #pragma unroll
    for(int i=0;i<4;i++){
      int lr = strip16 + quad*4 + i;
      sc_state[((size_t)bh*T_ + t0h + lr)*64 + nf*16+lq] = acc2[nf2][i];
    }
  }
}

// ---------------- MFMA fused window attention, 32-row half-chunk blocks (grid 64x4x2) ----------------
// Waves: sp = w>>1 owns 16-row strip; np = w&1 owns u/cv half. KV window per full chunk nt.
__global__ __launch_bounds__(256,2) void window_attn_mfma(
    const unsigned short* __restrict__ q_bf,
    const unsigned short* __restrict__ k_bf,
    const unsigned short* __restrict__ vt_bf,
    const float* __restrict__ sc_state,
    float* __restrict__ o,
    unsigned short* __restrict__ phi, unsigned short* __restrict__ plo)
{
  int bx=blockIdx.x, h=blockIdx.y, b=blockIdx.z;
  int nt = bx>>1, half = bx&1;
  int tid=threadIdx.x;
  int lane = tid & 63, w = tid >> 6;
  int quad = lane >> 4, lq = lane & 15;
  int sp = w >> 1, np = w & 1;
  int t0c = nt*64, t0h = t0c + half*32, bh = b*H_ + h;
  float slope = exp2f(-2.0f*(float)h);

  __shared__ unsigned short kv_lds[256*72];   // union: K 64x260 / VT 256x72
  __shared__ float S_lds[32*68];
  __shared__ unsigned short P_lds[32*72];
  __shared__ float m_lds[32], l_lds[32], al_lds[32];

  bf16x8 qf[8];
  {
    const unsigned short* qrow = q_bf + ((size_t)(b*T_ + t0h + 16*sp + lq))*D_ + h*CK_ + quad*8;
    #pragma unroll
    for(int ks=0; ks<8; ks++)
      qf[ks] = *(const bf16x8*)(const void*)(qrow + ks*32);
  }

  int r = tid >> 3, part = tid & 7;   // 8 threads per row, 32 rows
  {
    const float* scrow = sc_state + ((size_t)bh*T_ + t0h + r)*64 + part*8;
    float pm = -1e30f, sv[8];
    #pragma unroll
    for(int i=0;i<8;i++){ sv[i] = scrow[i]; pm = fmaxf(pm, sv[i]); }
    pm = fmaxf(pm, __shfl_xor(pm,1)); pm = fmaxf(pm, __shfl_xor(pm,2)); pm = fmaxf(pm, __shfl_xor(pm,4));
    float ps = 0.f;
    #pragma unroll
    for(int i=0;i<8;i++) ps += __expf(sv[i]-pm);
    ps += __shfl_xor(ps,1); ps += __shfl_xor(ps,2); ps += __shfl_xor(ps,4);
    if(part==0){ m_lds[r]=pm; l_lds[r]=ps; }
  }

  f32x4 o_acc[8];
  #pragma unroll
  for(int nv=0;nv<8;nv++) o_acc[nv] = (f32x4){0.f,0.f,0.f,0.f};
  __syncthreads();

  int jt0 = (nt>=8)? nt-8 : 0;
  for(int jt=jt0; jt<=nt; jt++){
    int j0 = jt*64;
    {
      int row = tid>>2, seg = tid&3;
      const unsigned short* src = k_bf + ((size_t)(b*T_ + j0 + row))*D_ + h*CK_ + seg*64;
      unsigned short* dst = kv_lds + row*260 + seg*64;
      #pragma unroll
      for(int i=0;i<8;i++) *(bf16x8*)(void*)(dst + i*8) = *(const bf16x8*)(const void*)(src + i*8);
    }
    __syncthreads();
    f32x4 sacc[2];
    #pragma unroll
    for(int n2=0;n2<2;n2++) sacc[n2] = (f32x4){0.f,0.f,0.f,0.f};
    #pragma unroll
    for(int n2=0;n2<2;n2++){
      int n = np*2 + n2;
      #pragma unroll
      for(int ks=0;ks<8;ks++){
        bf16x8 kf = *(const bf16x8*)(const void*)(kv_lds + (n*16+lq)*260 + ks*32 + quad*8);
        sacc[n2] = __builtin_amdgcn_mfma_f32_16x16x32_bf16(qf[ks], kf, sacc[n2], 0,0,0);
      }
    }
    #pragma unroll
    for(int n2=0;n2<2;n2++){
      int n = np*2+n2;
      int u = j0 + n*16 + lq;
      #pragma unroll
      for(int i=0;i<4;i++){
        int row = 16*sp + quad*4 + i;       // local 0..31
        int d = (t0h + row) - u;
        float val = (d>=0 && d<W_) ? sacc[n2][i] - slope*(float)d : -1e30f;
        S_lds[row*68 + n*16+lq] = val;
      }
    }
    __syncthreads();
    {
      float s8[8], tm = -1e30f;
      #pragma unroll
      for(int i=0;i<8;i++){ s8[i] = S_lds[r*68 + part*8 + i]; tm = fmaxf(tm, s8[i]); }
      tm = fmaxf(tm, __shfl_xor(tm,1)); tm = fmaxf(tm, __shfl_xor(tm,2)); tm = fmaxf(tm, __shfl_xor(tm,4));
      float m_old = m_lds[r];
      float m_new = fmaxf(m_old, tm);
      float alpha = __expf(m_old - m_new);
      float ts = 0.f;
      union { unsigned short u[8]; bf16x8 v; } pk;
      #pragma unroll
      for(int i=0;i<8;i++){ float p = __expf(s8[i]-m_new); ts += p; pk.u[i] = f2bf(p); }
      ts += __shfl_xor(ts,1); ts += __shfl_xor(ts,2); ts += __shfl_xor(ts,4);
      *(bf16x8*)(void*)&P_lds[r*72 + part*8] = pk.v;
      if(part==0){ m_lds[r] = m_new; l_lds[r] = l_lds[r]*alpha + ts; al_lds[r] = alpha; }
      #pragma unroll
      for(int pass=0; pass<4; pass++){
        int cv = (tid>>2) + 64*pass, useg = (tid&3)*16;
        const unsigned short* src = vt_bf + ((size_t)(bh*256 + cv))*T_ + j0 + useg;
        unsigned short* dst = kv_lds + cv*72 + useg;
        *(bf16x8*)(void*)(dst)   = *(const bf16x8*)(const void*)(src);
        *(bf16x8*)(void*)(dst+8) = *(const bf16x8*)(const void*)(src+8);
      }
    }
    __syncthreads();
    #pragma unroll
    for(int i=0;i<4;i++){
      float al = al_lds[16*sp+quad*4+i];
      #pragma unroll
      for(int nv=0;nv<8;nv++) o_acc[nv][i] *= al;
    }
    bf16x8 pa[2];
    #pragma unroll
    for(int k2=0;k2<2;k2++)
      pa[k2] = *(const bf16x8*)(const void*)&P_lds[(16*sp+lq)*72 + k2*32 + quad*8];
    #pragma unroll
    for(int nv=0;nv<8;nv++){
      int cvt = np*8 + nv;
      #pragma unroll
      for(int k2=0;k2<2;k2++){
        bf16x8 vb = *(const bf16x8*)(const void*)(kv_lds + (cvt*16+lq)*72 + k2*32 + quad*8);
        o_acc[nv] = __builtin_amdgcn_mfma_f32_16x16x32_bf16(pa[k2], vb, o_acc[nv], 0,0,0);
      }
    }
    __syncthreads();
  }
  #pragma unroll
  for(int i=0;i<4;i++){
    int row = 16*sp + quad*4 + i;
    float rl = 1.0f / l_lds[row];
    #pragma unroll
    for(int nv=0;nv<8;nv++){
      int cv = (np*8+nv)*16 + lq;
      o[((size_t)bh*T_ + t0h + row)*256 + cv] = o_acc[nv][i] * rl;
    }
  }
  {
    float mf = m_lds[r], rlf = 1.0f / l_lds[r];
    const float* scrow = sc_state + ((size_t)bh*T_ + t0h + r)*64 + part*8;
    size_t pb = ((size_t)bh*T_ + t0h + r)*64 + part*8;
    #pragma unroll
    for(int i=0;i<8;i++){
      float pv = __expf(scrow[i]-mf)*rlf;
      unsigned short hh, ll;
      split2(pv, hh, ll);
      phi[pb+i] = hh;
      plo[pb+i] = ll;
    }
  }
}

// ---------------- o += p @ SG + tril(p·g^T) @ V via MFMA ----------------
__global__ __launch_bounds__(256,1) void o_state_mfma(
    const unsigned short* __restrict__ phi, const unsigned short* __restrict__ plo,
    const float* __restrict__ g,
    const unsigned short* __restrict__ S2hi, const unsigned short* __restrict__ S2lo,
    const unsigned short* __restrict__ vt, const unsigned short* __restrict__ vtlo,
    float* __restrict__ o)
{
  __shared__ unsigned short gh_lds[64*72];
  __shared__ unsigned short gl_lds[64*72];
  __shared__ unsigned short Mh_lds[64*72];
  __shared__ unsigned short Ml_lds[64*72];
  int n=blockIdx.x, h=blockIdx.y, b=blockIdx.z;
  int tid=threadIdx.x, lane=tid&63, w=tid>>6;
  int quad=lane>>4, lq=lane&15;
  int t0=n*64, bh=b*H_+h, strip=w*16;

  // stage g chunk split to LDS [u][s]
  {
    int gu = tid>>2, gs0 = (tid&3)*16;
    const float* gr = g + ((size_t)(b*T_+t0+gu))*256 + h*64 + gs0;
    union{ unsigned short u[16]; bf16x8 v[2]; } GH, GL;
    #pragma unroll
    for(int j=0;j<16;j++) split2(gr[j], GH.u[j], GL.u[j]);
    *(bf16x8*)(void*)&gh_lds[gu*72+gs0]   = GH.v[0];
    *(bf16x8*)(void*)&gh_lds[gu*72+gs0+8] = GH.v[1];
    *(bf16x8*)(void*)&gl_lds[gu*72+gs0]   = GL.v[0];
    *(bf16x8*)(void*)&gl_lds[gu*72+gs0+8] = GL.v[1];
  }
  __syncthreads();

  // M strip (wave w owns rows strip..strip+15): M[t][u] = sum_s p[t][s]*g[u][s], tril
  {
    const unsigned short* ph = phi + ((size_t)bh*T_ + t0 + strip + lq)*64;
    const unsigned short* pl = plo + ((size_t)bh*T_ + t0 + strip + lq)*64;
    f32x4 ma[4];
    #pragma unroll
    for(int nf=0;nf<4;nf++) ma[nf] = (f32x4){0.f,0.f,0.f,0.f};
    #pragma unroll
    for(int ks=0;ks<2;ks++){
      bf16x8 pfh = *(const bf16x8*)(const void*)(ph + ks*32 + quad*8);
      bf16x8 pfl = *(const bf16x8*)(const void*)(pl + ks*32 + quad*8);
      #pragma unroll
      for(int nf=0;nf<4;nf++){
        bf16x8 gH = *(const bf16x8*)(const void*)&gh_lds[(nf*16+lq)*72 + ks*32 + quad*8];
        bf16x8 gL = *(const bf16x8*)(const void*)&gl_lds[(nf*16+lq)*72 + ks*32 + quad*8];
        ma[nf] = __builtin_amdgcn_mfma_f32_16x16x32_bf16(pfh, gH, ma[nf], 0,0,0);
        ma[nf] = __builtin_amdgcn_mfma_f32_16x16x32_bf16(pfh, gL, ma[nf], 0,0,0);
        ma[nf] = __builtin_amdgcn_mfma_f32_16x16x32_bf16(pfl, gH, ma[nf], 0,0,0);
      }
    }
    #pragma unroll
    for(int nf=0;nf<4;nf++){
      int u = nf*16 + lq;
      #pragma unroll
      for(int i=0;i<4;i++){
        int trow = strip + quad*4 + i;
        float val = (u <= trow) ? ma[nf][i] : 0.f;
        unsigned short hh, ll;
        split2(val, hh, ll);
        Mh_lds[trow*72 + u] = hh;
        Ml_lds[trow*72 + u] = ll;
      }
    }
  }
  __syncthreads();

  // o tile: wave w owns cols c0..c0+63
  f32x4 oacc[4][4];
  #pragma unroll
  for(int i=0;i<4;i++)
    #pragma unroll
    for(int j=0;j<4;j++) oacc[i][j] = (f32x4){0.f,0.f,0.f,0.f};
  int c0 = w*64;
  size_t sgbase = ((size_t)bh*NC_ + n)*16384;
  #pragma unroll
  for(int ks=0;ks<2;ks++){
    bf16x8 pAh[4], pAl[4], mAh[4], mAl[4];
    #pragma unroll
    for(int mi=0;mi<4;mi++){
      size_t po = ((size_t)bh*T_ + t0 + mi*16+lq)*64 + ks*32 + quad*8;
      pAh[mi] = *(const bf16x8*)(const void*)(phi + po);
      pAl[mi] = *(const bf16x8*)(const void*)(plo + po);
      mAh[mi] = *(const bf16x8*)(const void*)&Mh_lds[(mi*16+lq)*72 + ks*32 + quad*8];
      mAl[mi] = *(const bf16x8*)(const void*)&Ml_lds[(mi*16+lq)*72 + ks*32 + quad*8];
    }
    #pragma unroll
    for(int ni=0;ni<4;ni++){
      int c = c0 + ni*16 + lq;
      size_t so = sgbase + (size_t)c*64 + ks*32 + quad*8;
      bf16x8 sgH = *(const bf16x8*)(const void*)(S2hi + so);
      bf16x8 sgL = *(const bf16x8*)(const void*)(S2lo + so);
      size_t vo = ((size_t)(bh*256 + c))*T_ + t0 + ks*32 + quad*8;
      bf16x8 vH = *(const bf16x8*)(const void*)(vt + vo);
      bf16x8 vL = *(const bf16x8*)(const void*)(vtlo + vo);
      #pragma unroll
      for(int mi=0;mi<4;mi++){
        oacc[mi][ni] = __builtin_amdgcn_mfma_f32_16x16x32_bf16(pAh[mi], sgH, oacc[mi][ni], 0,0,0);
        oacc[mi][ni] = __builtin_amdgcn_mfma_f32_16x16x32_bf16(pAh[mi], sgL, oacc[mi][ni], 0,0,0);
        oacc[mi][ni] = __builtin_amdgcn_mfma_f32_16x16x32_bf16(pAl[mi], sgH, oacc[mi][ni], 0,0,0);
        oacc[mi][ni] = __builtin_amdgcn_mfma_f32_16x16x32_bf16(mAh[mi], vH, oacc[mi][ni], 0,0,0);
        oacc[mi][ni] = __builtin_amdgcn_mfma_f32_16x16x32_bf16(mAl[mi], vH, oacc[mi][ni], 0,0,0);
        oacc[mi][ni] = __builtin_amdgcn_mfma_f32_16x16x32_bf16(mAh[mi], vL, oacc[mi][ni], 0,0,0);
      }
    }
  }
  #pragma unroll
  for(int mi=0;mi<4;mi++)
    #pragma unroll
    for(int ni=0;ni<4;ni++)
      #pragma unroll
      for(int i=0;i<4;i++){
        int trow = mi*16 + quad*4 + i, c = c0 + ni*16 + lq;
        size_t oi = ((size_t)bh*T_ + t0 + trow)*256 + c;
        o[oi] += oacc[mi][ni][i];
      }
}

// ---------------- swish + rmsnorm, gather heads -> split bf16 hi/lo ----------------
__global__ void swish_rms_split_kernel(const float* __restrict__ o, const float* __restrict__ w,
                                       unsigned short* __restrict__ ohi, unsigned short* __restrict__ olo){
  int bt=blockIdx.x, tid=threadIdx.x;
  int b = bt >> 11, t = bt & 2047;
  float y[4]; float ss=0.f;
  #pragma unroll
  for(int hh=0;hh<4;hh++){
    float x = o[((size_t)(b*H_+hh)*T_ + t)*256 + tid];
    float yy = x / (1.f + expf(-x));
    y[hh]=yy; ss += yy*yy;
  }
  __shared__ float red[256];
  red[tid]=ss; __syncthreads();
  for(int s2=128;s2>0;s2>>=1){ if(tid<s2) red[tid]+=red[tid+s2]; __syncthreads(); }
  float r = rsqrtf(red[0]/1024.f + 1e-5f);
  #pragma unroll
  for(int hh=0;hh<4;hh++){
    unsigned short a,bq;
    split2(y[hh]*r*w[hh*256+tid], a, bq);
    ohi[(size_t)bt*1024 + hh*256 + tid] = a;
    olo[(size_t)bt*1024 + hh*256 + tid] = bq;
  }
}

extern "C" void kernel_launch(void* const* d_in, const int* in_sizes, int n_in,
                              void* d_out, int out_size, void* d_ws, size_t ws_size,
                              hipStream_t stream){
  const float* hidden = (const float*)d_in[0];
  const float* w_norm = (const float*)d_in[1];
  const float* Wq = (const float*)d_in[2];
  const float* Wk = (const float*)d_in[3];
  const float* Wv = (const float*)d_in[4];
  const float* Ws = (const float*)d_in[5];
  const float* Wg = (const float*)d_in[6];
  const float* Wo = (const float*)d_in[7];
  float* out = (float*)d_out;

  char* p = (char*)d_ws;
  auto alloc = [&](size_t bytes)->void*{ void* r = (void*)p; p += (bytes + 255) & ~(size_t)255; return r; };
  unsigned short* h_hi = (unsigned short*)alloc(8388608);   // (4096,1024) bf16; reused for o2_hi
  unsigned short* h_lo = (unsigned short*)alloc(8388608);   //               ; reused for o2_lo
  unsigned short* Wc_hi = (unsigned short*)alloc(11010048); // (5376,1024) bf16 [Wq;Wk;Ws;Wv;Wg;Wo]
  unsigned short* Wc_lo = (unsigned short*)alloc(11010048);
  unsigned short* vslot = (unsigned short*)alloc(16777216); // vtlo (8.39MB) + S2hi (8.39MB)
  float* g   = (float*)alloc(4194304);                      // (4096,256) f32 — kept alive for o_state
  float* P1  = (float*)alloc(16777216);                     // G^T@S chunks; o aliases after prefix_split
  float* P2  = (float*)alloc(16777216);                     // S1hi/S1lo early; G^T@V f32 mid
  float* sc  = (float*)alloc(4194304);                      // (8,2048,64)
  float* ps  = (float*)alloc(4194304);                      // GThi/GTlo early; phi/plo late
  unsigned short* qks = (unsigned short*)alloc(25165824);   // q|k|s bf16, 3x(4096,1024)
  unsigned short* vt  = (unsigned short*)alloc(8388608);    // V^T bf16 hi (8,256,2048)

  unsigned short* vtlo = vslot;                    // V^T bf16 lo
  unsigned short* S2hi = vslot + 4194304;          // SG prefix hi (c-major chunks)
  unsigned short* q_bf = qks;
  unsigned short* k_bf = qks + 4194304;
  unsigned short* s_bf = qks + 8388608;
  unsigned short* S2lo = s_bf;                     // s_bf dead after sc_state; S2lo born after
  float* o = P1;                                   // P1 dead after chunk_prefix_split
  unsigned short* S1hi = (unsigned short*)P2;      // consumed by sc_state before chunk_outer_vt writes P2
  unsigned short* S1lo = S1hi + 4194304;
  unsigned short* GThi = (unsigned short*)ps;      // consumed by chunk_outer_vt; then phi/plo overwrite
  unsigned short* GTlo = GThi + 1048576;
  unsigned short* phi  = (unsigned short*)ps;
  unsigned short* plo  = phi + 1048576;

  rmsnorm_split_kernel<<<4096,256,0,stream>>>(hidden, w_norm, h_hi, h_lo);
  wsplit_kernel<<<5376,256,0,stream>>>(Wq, Wk, Ws, Wv, Wg, Wo, Wc_hi, Wc_lo);
  gemm_bf16s<<<dim3(34,32),256,0,stream>>>(h_hi, h_lo, Wc_hi, Wc_lo,
                                           qks, vt, vtlo, g, nullptr, 0);
  softmax256_kernel<<<4096,256,0,stream>>>(g);
  dim3 gc(32,4,2);
  dim3 gch(64,4,2);
  g_transpose_split_kernel<<<gc,256,0,stream>>>(g, GThi, GTlo);
  chunk_outer_mfma<<<gc,256,0,stream>>>(GThi, GTlo, s_bf, P1);           // P1 = G^T @ S (s-major)
  chunk_prefix_split_kernel<<<512,256,0,stream>>>(P1, S1hi, S1lo);
  sc_state_mfma<<<gch,256,0,stream>>>(q_bf, s_bf, S1hi, S1lo, GThi, GTlo, sc);
  chunk_outer_vt<<<gc,256,0,stream>>>(GThi, GTlo, vt, vtlo, P2);         // P2 = G^T @ V (c-major)
  chunk_prefix_split_kernel<<<512,256,0,stream>>>(P2, S2hi, S2lo);
  window_attn_mfma<<<gch,256,0,stream>>>(q_bf, k_bf, vt, sc, o, phi, plo);
  o_state_mfma<<<gc,256,0,stream>>>(phi, plo, g, S2hi, S2lo, vt, vtlo, o);
  swish_rms_split_kernel<<<4096,256,0,stream>>>(o, w_norm, h_hi, h_lo);
  gemm_bf16s<<<dim3(8,32),256,0,stream>>>(h_hi, h_lo, Wc_hi + (size_t)4352*1024, Wc_lo + (size_t)4352*1024,
                                          nullptr, nullptr, nullptr, nullptr, out, 1);
}

// Round 11
// 391.618 us; speedup vs baseline: 1.0279x; 1.0279x over previous
//
#include <hip/hip_runtime.h>
#include <stdint.h>

#define B_  2
#define T_  2048
#define D_  1024
#define H_  4
#define S_  64
#define W_  512
#define CK_ 256
#define NC_ 32      // T_/64 chunks

typedef __attribute__((ext_vector_type(8))) short bf16x8;
typedef __attribute__((ext_vector_type(4))) float f32x4;
typedef __attribute__((ext_vector_type(4))) unsigned short u16x4;

__device__ __forceinline__ float bf2f(unsigned short u){ return __uint_as_float(((unsigned int)u)<<16); }
__device__ __forceinline__ unsigned short f2bf(float f){
  unsigned int u = __float_as_uint(f);
  u += 0x7fffu + ((u>>16)&1u);
  return (unsigned short)(u>>16);
}
__device__ __forceinline__ void split2(float y, unsigned short& hi, unsigned short& lo){
  hi = f2bf(y);
  lo = f2bf(y - bf2f(hi));
}

// async global->LDS, 16B per lane; lds base must be wave-uniform (HW adds lane*16)
__device__ __forceinline__ void gl_lds16(const unsigned short* g, unsigned short* l){
  __builtin_amdgcn_global_load_lds(
      (const __attribute__((address_space(1))) unsigned int*)g,
      (__attribute__((address_space(3))) unsigned int*)l, 16, 0, 0);
}

// ---------------- RMSNorm: x(B*T,D) -> split bf16 hi/lo ----------------
__global__ void rmsnorm_split_kernel(const float* __restrict__ x, const float* __restrict__ w,
                                     unsigned short* __restrict__ ohi, unsigned short* __restrict__ olo){
  int row = blockIdx.x, tid = threadIdx.x;
  const float* xr = x + (size_t)row*D_;
  float v0=xr[tid], v1=xr[tid+256], v2=xr[tid+512], v3=xr[tid+768];
  __shared__ float red[256];
  red[tid] = v0*v0+v1*v1+v2*v2+v3*v3;
  __syncthreads();
  for(int s=128;s>0;s>>=1){ if(tid<s) red[tid]+=red[tid+s]; __syncthreads(); }
  float r = rsqrtf(red[0]/(float)D_ + 1e-5f);
  size_t base = (size_t)row*D_;
  float y0=v0*r*w[tid], y1=v1*r*w[tid+256], y2=v2*r*w[tid+512], y3=v3*r*w[tid+768];
  unsigned short hh, ll;
  split2(y0,hh,ll); ohi[base+tid]=hh;     olo[base+tid]=ll;
  split2(y1,hh,ll); ohi[base+tid+256]=hh; olo[base+tid+256]=ll;
  split2(y2,hh,ll); ohi[base+tid+512]=hh; olo[base+tid+512]=ll;
  split2(y3,hh,ll); ohi[base+tid+768]=hh; olo[base+tid+768]=ll;
}

// ---------------- weight concat + split: rows [Wq;Wk;Ws;Wv;Wg;Wo] ----------------
__global__ void wsplit_kernel(const float* __restrict__ Wq, const float* __restrict__ Wk,
                              const float* __restrict__ Ws, const float* __restrict__ Wv,
                              const float* __restrict__ Wg, const float* __restrict__ Wo,
                              unsigned short* __restrict__ whi, unsigned short* __restrict__ wlo){
  int row = blockIdx.x, tid = threadIdx.x;
  const float* src;
  if(row < 1024)      src = Wq + (size_t)row*1024;
  else if(row < 2048) src = Wk + (size_t)(row-1024)*1024;
  else if(row < 3072) src = Ws + (size_t)(row-2048)*1024;
  else if(row < 4096) src = Wv + (size_t)(row-3072)*1024;
  else if(row < 4352) src = Wg + (size_t)(row-4096)*1024;
  else                src = Wo + (size_t)(row-4352)*1024;
  f32x4 vv = *(const f32x4*)(src + tid*4);
  u16x4 hh, ll;
  #pragma unroll
  for(int j=0;j<4;j++){ unsigned short a,b; split2(vv[j],a,b); hh[j]=a; ll[j]=b; }
  *(u16x4*)(whi + (size_t)row*1024 + tid*4) = hh;
  *(u16x4*)(wlo + (size_t)row*1024 + tid*4) = ll;
}

// ---------------- split-bf16 MFMA GEMM: C[M,4352] = A[4096,1024] * Wcat^T ----------------
__global__ __launch_bounds__(256,2) void gemm_bf16s(
    const unsigned short* __restrict__ Ahi, const unsigned short* __restrict__ Alo,
    const unsigned short* __restrict__ Whi, const unsigned short* __restrict__ Wlo,
    unsigned short* __restrict__ qks, unsigned short* __restrict__ vt,
    unsigned short* __restrict__ vtlo, float* __restrict__ gout,
    float* __restrict__ Cf, int mode)
{
  __shared__ unsigned short Ah_s[128*64];
  __shared__ unsigned short Al_s[128*64];
  __shared__ unsigned short Bh_s[128*64];
  __shared__ unsigned short Bl_s[128*64];
  int tid = threadIdx.x;
  int lane = tid & 63, w = tid >> 6;
  int quad = lane >> 4, lq = lane & 15;
  int wr = w >> 1, wc = w & 1;
  int bid = blockIdx.y*gridDim.x + blockIdx.x;
  int row0, col0;
  if(mode == 0){
    int xcd = bid & 7, slot = bid >> 3;
    int rx = xcd & 3, cx = xcd >> 2;
    int sr = slot / 17, sc2 = slot % 17;
    row0 = (rx*8 + sr)*128;
    col0 = (cx*17 + sc2)*128;
  } else {
    int q8 = (gridDim.x*gridDim.y) >> 3;
    int wg = (bid & 7)*q8 + (bid >> 3);
    col0 = (wg % gridDim.x)*128;
    row0 = (wg / gridDim.x)*128;
  }

  int l8 = lane >> 3;
  int chk = lane & 7;

  f32x4 acc[4][4];
  #pragma unroll
  for(int i=0;i<4;i++)
    #pragma unroll
    for(int j=0;j<4;j++) acc[i][j] = (f32x4){0.f,0.f,0.f,0.f};

  for(int kt=0; kt<1024; kt+=64){
    __syncthreads();
    #pragma unroll
    for(int j=0;j<4;j++){
      int rl = w*32 + j*8 + l8;
      int sc = (chk ^ (rl & 7))*8;
      int lbase = (w*32 + j*8)*64;
      gl_lds16(Ahi + (size_t)(row0+rl)*1024 + kt + sc, Ah_s + lbase);
      gl_lds16(Alo + (size_t)(row0+rl)*1024 + kt + sc, Al_s + lbase);
      gl_lds16(Whi + (size_t)(col0+rl)*1024 + kt + sc, Bh_s + lbase);
      gl_lds16(Wlo + (size_t)(col0+rl)*1024 + kt + sc, Bl_s + lbase);
    }
    __syncthreads();
    #pragma unroll
    for(int ks=0;ks<2;ks++){
      bf16x8 afh[4], afl[4], bfh[4], bfl[4];
      #pragma unroll
      for(int i=0;i<4;i++){
        int Ra = wr*64+i*16+lq;
        int ca = ((ks*4+quad) ^ (Ra&7))*8;
        afh[i] = *(const bf16x8*)(const void*)(Ah_s + Ra*64 + ca);
        afl[i] = *(const bf16x8*)(const void*)(Al_s + Ra*64 + ca);
        int Rb = wc*64+i*16+lq;
        int cb = ((ks*4+quad) ^ (Rb&7))*8;
        bfh[i] = *(const bf16x8*)(const void*)(Bh_s + Rb*64 + cb);
        bfl[i] = *(const bf16x8*)(const void*)(Bl_s + Rb*64 + cb);
      }
      #pragma unroll
      for(int mi=0;mi<4;mi++)
        #pragma unroll
        for(int ni=0;ni<4;ni++){
          acc[mi][ni] = __builtin_amdgcn_mfma_f32_16x16x32_bf16(afh[mi], bfh[ni], acc[mi][ni], 0,0,0);
          acc[mi][ni] = __builtin_amdgcn_mfma_f32_16x16x32_bf16(afh[mi], bfl[ni], acc[mi][ni], 0,0,0);
          acc[mi][ni] = __builtin_amdgcn_mfma_f32_16x16x32_bf16(afl[mi], bfh[ni], acc[mi][ni], 0,0,0);
        }
    }
  }

  int rbase = row0 + wr*64, cbase = col0 + wc*64;
  if(mode == 1){
    #pragma unroll
    for(int mi=0;mi<4;mi++)
      #pragma unroll
      for(int ni=0;ni<4;ni++)
        #pragma unroll
        for(int i=0;i<4;i++)
          Cf[(size_t)(rbase+mi*16+quad*4+i)*1024 + cbase+ni*16+lq] = acc[mi][ni][i];
  } else if(col0 < 3072){
    unsigned short* dst = qks + (size_t)(col0>>10)*4194304;
    #pragma unroll
    for(int mi=0;mi<4;mi++)
      #pragma unroll
      for(int ni=0;ni<4;ni++)
        #pragma unroll
        for(int i=0;i<4;i++){
          int rr = rbase+mi*16+quad*4+i, cc = (cbase+ni*16+lq) & 1023;
          dst[(size_t)rr*1024 + cc] = f2bf(acc[mi][ni][i]);
        }
  } else if(col0 < 4096){
    #pragma unroll
    for(int mi=0;mi<4;mi++)
      #pragma unroll
      for(int ni=0;ni<4;ni++)
        #pragma unroll
        for(int i=0;i<4;i++){
          int rr = rbase+mi*16+quad*4+i, cl = (cbase+ni*16+lq) & 1023;
          unsigned short hh2, ll2;
          split2(acc[mi][ni][i], hh2, ll2);
          int hh = cl>>8, cv = cl&255, bb = rr>>11, tt = rr&2047;
          size_t ti = ((size_t)((bb*H_+hh)*256 + cv))*T_ + tt;
          vt[ti] = hh2;
          vtlo[ti] = ll2;
        }
  } else {
    #pragma unroll
    for(int mi=0;mi<4;mi++)
      #pragma unroll
      for(int ni=0;ni<4;ni++)
        #pragma unroll
        for(int i=0;i<4;i++){
          int rr = rbase+mi*16+quad*4+i, cl = cbase+ni*16+lq - 4096;
          gout[(size_t)rr*256 + cl] = acc[mi][ni][i];
        }
  }
}

// ---------------- softmax over 256 (in place), one row per block ----------------
__global__ void softmax256_kernel(float* __restrict__ g){
  int row = blockIdx.x, tid = threadIdx.x;
  float x = g[(size_t)row*256+tid];
  __shared__ float red[256];
  red[tid]=x; __syncthreads();
  for(int s=128;s>0;s>>=1){ if(tid<s) red[tid]=fmaxf(red[tid],red[tid+s]); __syncthreads(); }
  float m = red[0]; __syncthreads();
  float e = expf(x-m);
  red[tid]=e; __syncthreads();
  for(int s=128;s>0;s>>=1){ if(tid<s) red[tid]+=red[tid+s]; __syncthreads(); }
  g[(size_t)row*256+tid] = e/red[0];
}

// ---------------- chunk outer (S path): out[s][c] = sum_u G[u,s]*S[u,c] ----------------
__global__ __launch_bounds__(256,1) void chunk_outer_mfma(
    const unsigned short* __restrict__ gthi, const unsigned short* __restrict__ gtlo,
    const unsigned short* __restrict__ s_bf, float* __restrict__ out)
{
  __shared__ unsigned short xh_lds[256*72];
  int n=blockIdx.x, h=blockIdx.y, b=blockIdx.z;
  int tid=threadIdx.x, lane=tid&63, w=tid>>6;
  int quad=lane>>4, lq=lane&15;
  int t0=n*64, bh=b*H_+h;

  const unsigned short* sb = s_bf + (size_t)(b*T_+t0)*D_ + h*CK_ + tid;
  for(int p2=0;p2<8;p2++){
    union{ unsigned short u[8]; bf16x8 v8; } r8;
    #pragma unroll
    for(int j=0;j<8;j++)
      r8.u[j] = sb[(size_t)(p2*8+j)*D_];
    *(bf16x8*)(void*)&xh_lds[tid*72 + p2*8] = r8.v8;
  }
  __syncthreads();

  size_t gtbase = ((size_t)bh*NC_ + n)*64;
  f32x4 acc[4][4];
  #pragma unroll
  for(int i=0;i<4;i++)
    #pragma unroll
    for(int j=0;j<4;j++) acc[i][j] = (f32x4){0.f,0.f,0.f,0.f};

  #pragma unroll
  for(int ks=0; ks<2; ks++){
    bf16x8 ah[4], al[4], bh4[4];
    #pragma unroll
    for(int mi=0;mi<4;mi++){
      ah[mi] = *(const bf16x8*)(const void*)(gthi + (gtbase + mi*16+lq)*64 + ks*32 + quad*8);
      al[mi] = *(const bf16x8*)(const void*)(gtlo + (gtbase + mi*16+lq)*64 + ks*32 + quad*8);
    }
    #pragma unroll
    for(int ni=0;ni<4;ni++)
      bh4[ni] = *(const bf16x8*)(const void*)&xh_lds[(w*64+ni*16+lq)*72 + ks*32 + quad*8];
    #pragma unroll
    for(int mi=0;mi<4;mi++)
      #pragma unroll
      for(int ni=0;ni<4;ni++){
        acc[mi][ni] = __builtin_amdgcn_mfma_f32_16x16x32_bf16(ah[mi], bh4[ni], acc[mi][ni], 0,0,0);
        acc[mi][ni] = __builtin_amdgcn_mfma_f32_16x16x32_bf16(al[mi], bh4[ni], acc[mi][ni], 0,0,0);
      }
  }
  size_t obase = ((size_t)bh*NC_ + n)*16384;
  #pragma unroll
  for(int mi=0;mi<4;mi++)
    #pragma unroll
    for(int ni=0;ni<4;ni++)
      #pragma unroll
      for(int i=0;i<4;i++){
        int s = mi*16 + quad*4 + i, c = w*64 + ni*16 + lq;
        out[obase + (size_t)s*256 + c] = acc[mi][ni][i];
      }
}

// ---------------- chunk outer (V path): out[c][s] = sum_u G[u,s]*V[u,c] ----------------
__global__ __launch_bounds__(256,1) void chunk_outer_vt(
    const unsigned short* __restrict__ gthi, const unsigned short* __restrict__ gtlo,
    const unsigned short* __restrict__ vt, const unsigned short* __restrict__ vtlo,
    float* __restrict__ out)
{
  int n=blockIdx.x, h=blockIdx.y, b=blockIdx.z;
  int tid=threadIdx.x, lane=tid&63, w=tid>>6;
  int quad=lane>>4, lq=lane&15;
  int t0=n*64, bh=b*H_+h;
  size_t gtbase = ((size_t)bh*NC_ + n)*64;
  f32x4 acc[4][4];
  #pragma unroll
  for(int i=0;i<4;i++)
    #pragma unroll
    for(int j=0;j<4;j++) acc[i][j] = (f32x4){0.f,0.f,0.f,0.f};

  #pragma unroll
  for(int ks=0; ks<2; ks++){
    bf16x8 ah[4], al[4];
    #pragma unroll
    for(int mi=0;mi<4;mi++){
      ah[mi] = *(const bf16x8*)(const void*)(gthi + (gtbase + mi*16+lq)*64 + ks*32 + quad*8);
      al[mi] = *(const bf16x8*)(const void*)(gtlo + (gtbase + mi*16+lq)*64 + ks*32 + quad*8);
    }
    #pragma unroll
    for(int ni=0;ni<4;ni++){
      size_t vo = ((size_t)(bh*256 + w*64 + ni*16 + lq))*T_ + t0 + ks*32 + quad*8;
      bf16x8 vh = *(const bf16x8*)(const void*)(vt + vo);
      bf16x8 vl = *(const bf16x8*)(const void*)(vtlo + vo);
      #pragma unroll
      for(int mi=0;mi<4;mi++){
        acc[mi][ni] = __builtin_amdgcn_mfma_f32_16x16x32_bf16(ah[mi], vh, acc[mi][ni], 0,0,0);
        acc[mi][ni] = __builtin_amdgcn_mfma_f32_16x16x32_bf16(al[mi], vh, acc[mi][ni], 0,0,0);
        acc[mi][ni] = __builtin_amdgcn_mfma_f32_16x16x32_bf16(ah[mi], vl, acc[mi][ni], 0,0,0);
      }
    }
  }
  size_t obase = ((size_t)bh*NC_ + n)*16384;
  #pragma unroll
  for(int mi=0;mi<4;mi++)
    #pragma unroll
    for(int ni=0;ni<4;ni++){
      int c = w*64 + ni*16 + lq, s0 = mi*16 + quad*4;
      *(f32x4*)&out[obase + (size_t)c*64 + s0] = acc[mi][ni];
    }
}

// ---------------- exclusive prefix over chunks -> split bf16 hi/lo ----------------
__global__ void chunk_prefix_split_kernel(const float* __restrict__ arr,
    unsigned short* __restrict__ hi, unsigned short* __restrict__ lo){
  int idx = blockIdx.x*256 + threadIdx.x;
  int bh = idx >> 14, e = idx & 16383;
  float run = 0.f;
  size_t base = (size_t)bh*NC_*16384 + e;
  for(int n=0;n<NC_;n++){
    size_t a = base + (size_t)n*16384;
    float t = arr[a];
    unsigned short hh, ll;
    split2(run, hh, ll);
    hi[a] = hh; lo[a] = ll;
    run += t;
  }
}

// ---------------- g (B*T,256) -> GT[bh*NC+n][s][u] split bf16 hi/lo ----------------
__global__ __launch_bounds__(256) void g_transpose_split_kernel(const float* __restrict__ g,
    unsigned short* __restrict__ gthi, unsigned short* __restrict__ gtlo){
  int n=blockIdx.x, h=blockIdx.y, b=blockIdx.z;
  int tid=threadIdx.x, t0=n*64;
  __shared__ float tt[64][65];
  #pragma unroll
  for(int p=0;p<16;p++){
    int u = (tid>>6) + p*4, s = tid&63;
    tt[s][u] = g[((size_t)(b*T_ + t0 + u))*256 + h*64 + s];
  }
  __syncthreads();
  size_t base = ((size_t)(b*H_+h)*NC_ + n)*64;
  #pragma unroll
  for(int p=0;p<16;p++){
    int s = (tid>>6) + p*4, u = tid&63;
    unsigned short hh, ll;
    split2(tt[s][u], hh, ll);
    gthi[(base+s)*64 + u] = hh;
    gtlo[(base+s)*64 + u] = ll;
  }
}

// ---------------- sc_state via MFMA (split-bf16, fp32-class numerics) ----------------
__global__ __launch_bounds__(256,1) void sc_state_mfma(
    const unsigned short* __restrict__ q_bf,
    const unsigned short* __restrict__ s_bf,
    const unsigned short* __restrict__ S1hi, const unsigned short* __restrict__ S1lo,
    const unsigned short* __restrict__ gthi, const unsigned short* __restrict__ gtlo,
    float* __restrict__ sc_state)
{
  int n=blockIdx.x, h=blockIdx.y, b=blockIdx.z;
  int tid=threadIdx.x, lane=tid&63, w=tid>>6;
  int quad=lane>>4, lq=lane&15;
  int t0=n*64, bh=b*H_+h, strip=w*16;

  __shared__ unsigned short A_hi[64*72];
  __shared__ unsigned short A_lo[64*72];

  bf16x8 qf[8];
  const unsigned short* qrow = q_bf + ((size_t)(b*T_ + t0 + strip + lq))*D_ + h*CK_ + quad*8;
  #pragma unroll
  for(int ks=0;ks<8;ks++) qf[ks] = *(const bf16x8*)(const void*)(qrow + ks*32);

  const unsigned short* sbase = s_bf + ((size_t)(b*T_ + t0))*D_ + h*CK_;
  f32x4 a1[4];
  #pragma unroll
  for(int nf=0;nf<4;nf++) a1[nf] = (f32x4){0.f,0.f,0.f,0.f};
  #pragma unroll
  for(int ks=0;ks<8;ks++){
    #pragma unroll
    for(int nf=0;nf<4;nf++){
      bf16x8 sf = *(const bf16x8*)(const void*)(sbase + (size_t)(nf*16+lq)*D_ + ks*32 + quad*8);
      a1[nf] = __builtin_amdgcn_mfma_f32_16x16x32_bf16(qf[ks], sf, a1[nf], 0,0,0);
    }
  }
  #pragma unroll
  for(int nf=0;nf<4;nf++){
    int u = nf*16 + lq;
    #pragma unroll
    for(int i=0;i<4;i++){
      int trow = strip + quad*4 + i;
      float val = (u <= trow) ? a1[nf][i] : 0.f;
      unsigned short hh, ll;
      split2(val, hh, ll);
      A_hi[trow*72 + u] = hh;
      A_lo[trow*72 + u] = ll;
    }
  }
  __syncthreads();

  bf16x8 afh[2], afl[2];
  #pragma unroll
  for(int ks=0;ks<2;ks++){
    afh[ks] = *(const bf16x8*)(const void*)&A_hi[(strip+lq)*72 + ks*32 + quad*8];
    afl[ks] = *(const bf16x8*)(const void*)&A_lo[(strip+lq)*72 + ks*32 + quad*8];
  }

  size_t s1base = ((size_t)bh*NC_ + n)*16384;
  size_t gtbase = ((size_t)bh*NC_ + n)*64;
  f32x4 acc2[4];
  #pragma unroll
  for(int nf=0;nf<4;nf++) acc2[nf] = (f32x4){0.f,0.f,0.f,0.f};
  #pragma unroll
  for(int ks=0;ks<8;ks++){
    #pragma unroll
    for(int nf=0;nf<4;nf++){
      size_t off = s1base + (size_t)(nf*16+lq)*256 + ks*32 + quad*8;
      bf16x8 b1 = *(const bf16x8*)(const void*)(S1hi + off);
      acc2[nf] = __builtin_amdgcn_mfma_f32_16x16x32_bf16(qf[ks], b1, acc2[nf], 0,0,0);
      bf16x8 b2 = *(const bf16x8*)(const void*)(S1lo + off);
      acc2[nf] = __builtin_amdgcn_mfma_f32_16x16x32_bf16(qf[ks], b2, acc2[nf], 0,0,0);
    }
  }
  #pragma unroll
  for(int ks=0;ks<2;ks++){
    #pragma unroll
    for(int nf=0;nf<4;nf++){
      size_t off = (gtbase + nf*16+lq)*64 + ks*32 + quad*8;
      bf16x8 gh = *(const bf16x8*)(const void*)(gthi + off);
      bf16x8 gl = *(const bf16x8*)(const void*)(gtlo + off);
      acc2[nf] = __builtin_amdgcn_mfma_f32_16x16x32_bf16(afh[ks], gh, acc2[nf], 0,0,0);
      acc2[nf] = __builtin_amdgcn_mfma_f32_16x16x32_bf16(afh[ks], gl, acc2[nf], 0,0,0);
      acc2[nf] = __builtin_amdgcn_mfma_f32_16x16x32_bf16(afl[ks], gh, acc2[nf], 0,0,0);
    }
  }
  #pragma unroll
  for(int nf=0;nf<4;nf++){
    #pragma unroll
    for(int i=0;i<4;i++){
      int trow = strip + quad*4 + i;
      sc_state[((size_t)bh*T_ + t0 + trow)*64 + nf*16+lq] = acc2[nf][i];
    }
  }
}

// ---------------- MFMA fused window attention, 512 threads / 8 waves ----------------
// One block per 64-row chunk (staging once); wave (sp=w>>1) owns 16-row strip,
// np=w&1 owns u/cv half. Softmax uses 8-lane groups (validated in round 10).
__global__ __launch_bounds__(512,1) void window_attn_mfma(
    const unsigned short* __restrict__ q_bf,
    const unsigned short* __restrict__ k_bf,
    const unsigned short* __restrict__ vt_bf,
    const float* __restrict__ sc_state,
    float* __restrict__ o,
    unsigned short* __restrict__ phi, unsigned short* __restrict__ plo)
{
  int nt=blockIdx.x, h=blockIdx.y, b=blockIdx.z;
  int tid=threadIdx.x;
  int lane = tid & 63, w = tid >> 6;
  int quad = lane >> 4, lq = lane & 15;
  int sp = w >> 1, np = w & 1;
  int t0 = nt*64, bh = b*H_ + h;
  float slope = exp2f(-2.0f*(float)h);

  __shared__ unsigned short kv_lds[256*72];   // union: K 64x260 (16640) / VT 256x72 (18432)
  __shared__ float S_lds[64*68];
  __shared__ unsigned short P_lds[64*72];
  __shared__ float m_lds[64], l_lds[64], al_lds[64];

  bf16x8 qf[8];
  {
    const unsigned short* qrow = q_bf + ((size_t)(b*T_ + t0 + 16*sp + lq))*D_ + h*CK_ + quad*8;
    #pragma unroll
    for(int ks=0; ks<8; ks++)
      qf[ks] = *(const bf16x8*)(const void*)(qrow + ks*32);
  }

  int r = tid >> 3, part = tid & 7;   // 8 threads per row, 64 rows
  {
    const float* scrow = sc_state + ((size_t)bh*T_ + t0 + r)*64 + part*8;
    float pm = -1e30f, sv[8];
    #pragma unroll
    for(int i=0;i<8;i++){ sv[i] = scrow[i]; pm = fmaxf(pm, sv[i]); }
    pm = fmaxf(pm, __shfl_xor(pm,1)); pm = fmaxf(pm, __shfl_xor(pm,2)); pm = fmaxf(pm, __shfl_xor(pm,4));
    float ps = 0.f;
    #pragma unroll
    for(int i=0;i<8;i++) ps += __expf(sv[i]-pm);
    ps += __shfl_xor(ps,1); ps += __shfl_xor(ps,2); ps += __shfl_xor(ps,4);
    if(part==0){ m_lds[r]=pm; l_lds[r]=ps; }
  }

  f32x4 o_acc[8];
  #pragma unroll
  for(int nv=0;nv<8;nv++) o_acc[nv] = (f32x4){0.f,0.f,0.f,0.f};
  __syncthreads();

  int jt0 = (nt>=8)? nt-8 : 0;
  for(int jt=jt0; jt<=nt; jt++){
    int j0 = jt*64;
    {
      int row = tid>>3, seg = tid&7;     // 512 threads: 64B per thread
      const unsigned short* src = k_bf + ((size_t)(b*T_ + j0 + row))*D_ + h*CK_ + seg*32;
      unsigned short* dst = kv_lds + row*260 + seg*32;
      #pragma unroll
      for(int i=0;i<4;i++) *(bf16x8*)(void*)(dst + i*8) = *(const bf16x8*)(const void*)(src + i*8);
    }
    __syncthreads();
    f32x4 sacc[2];
    #pragma unroll
    for(int n2=0;n2<2;n2++) sacc[n2] = (f32x4){0.f,0.f,0.f,0.f};
    #pragma unroll
    for(int n2=0;n2<2;n2++){
      int n = np*2 + n2;
      #pragma unroll
      for(int ks=0;ks<8;ks++){
        bf16x8 kf = *(const bf16x8*)(const void*)(kv_lds + (n*16+lq)*260 + ks*32 + quad*8);
        sacc[n2] = __builtin_amdgcn_mfma_f32_16x16x32_bf16(qf[ks], kf, sacc[n2], 0,0,0);
      }
    }
    #pragma unroll
    for(int n2=0;n2<2;n2++){
      int n = np*2+n2;
      int u = j0 + n*16 + lq;
      #pragma unroll
      for(int i=0;i<4;i++){
        int row = 16*sp + quad*4 + i;     // chunk-local 0..63
        int d = (t0 + row) - u;
        float val = (d>=0 && d<W_) ? sacc[n2][i] - slope*(float)d : -1e30f;
        S_lds[row*68 + n*16+lq] = val;
      }
    }
    __syncthreads();
    {
      float s8[8], tm = -1e30f;
      #pragma unroll
      for(int i=0;i<8;i++){ s8[i] = S_lds[r*68 + part*8 + i]; tm = fmaxf(tm, s8[i]); }
      tm = fmaxf(tm, __shfl_xor(tm,1)); tm = fmaxf(tm, __shfl_xor(tm,2)); tm = fmaxf(tm, __shfl_xor(tm,4));
      float m_old = m_lds[r];
      float m_new = fmaxf(m_old, tm);
      float alpha = __expf(m_old - m_new);
      float ts = 0.f;
      union { unsigned short u[8]; bf16x8 v; } pk;
      #pragma unroll
      for(int i=0;i<8;i++){ float p = __expf(s8[i]-m_new); ts += p; pk.u[i] = f2bf(p); }
      ts += __shfl_xor(ts,1); ts += __shfl_xor(ts,2); ts += __shfl_xor(ts,4);
      *(bf16x8*)(void*)&P_lds[r*72 + part*8] = pk.v;
      if(part==0){ m_lds[r] = m_new; l_lds[r] = l_lds[r]*alpha + ts; al_lds[r] = alpha; }
      #pragma unroll
      for(int pass=0; pass<2; pass++){
        int cv = (tid>>2) + 128*pass, useg = (tid&3)*16;
        const unsigned short* src = vt_bf + ((size_t)(bh*256 + cv))*T_ + j0 + useg;
        unsigned short* dst = kv_lds + cv*72 + useg;
        *(bf16x8*)(void*)(dst)   = *(const bf16x8*)(const void*)(src);
        *(bf16x8*)(void*)(dst+8) = *(const bf16x8*)(const void*)(src+8);
      }
    }
    __syncthreads();
    #pragma unroll
    for(int i=0;i<4;i++){
      float al = al_lds[16*sp+quad*4+i];
      #pragma unroll
      for(int nv=0;nv<8;nv++) o_acc[nv][i] *= al;
    }
    bf16x8 pa[2];
    #pragma unroll
    for(int k2=0;k2<2;k2++)
      pa[k2] = *(const bf16x8*)(const void*)&P_lds[(16*sp+lq)*72 + k2*32 + quad*8];
    #pragma unroll
    for(int nv=0;nv<8;nv++){
      int cvt = np*8 + nv;
      #pragma unroll
      for(int k2=0;k2<2;k2++){
        bf16x8 vb = *(const bf16x8*)(const void*)(kv_lds + (cvt*16+lq)*72 + k2*32 + quad*8);
        o_acc[nv] = __builtin_amdgcn_mfma_f32_16x16x32_bf16(pa[k2], vb, o_acc[nv], 0,0,0);
      }
    }
    __syncthreads();
  }
  #pragma unroll
  for(int i=0;i<4;i++){
    int row = 16*sp + quad*4 + i;
    float rl = 1.0f / l_lds[row];
    #pragma unroll
    for(int nv=0;nv<8;nv++){
      int cv = (np*8+nv)*16 + lq;
      o[((size_t)bh*T_ + t0 + row)*256 + cv] = o_acc[nv][i] * rl;
    }
  }
  {
    float mf = m_lds[r], rlf = 1.0f / l_lds[r];
    const float* scrow = sc_state + ((size_t)bh*T_ + t0 + r)*64 + part*8;
    size_t pb = ((size_t)bh*T_ + t0 + r)*64 + part*8;
    #pragma unroll
    for(int i=0;i<8;i++){
      float pv = __expf(scrow[i]-mf)*rlf;
      unsigned short hh, ll;
      split2(pv, hh, ll);
      phi[pb+i] = hh;
      plo[pb+i] = ll;
    }
  }
}

// ---------------- o += p @ SG + tril(p·g^T) @ V via MFMA ----------------
__global__ __launch_bounds__(256,1) void o_state_mfma(
    const unsigned short* __restrict__ phi, const unsigned short* __restrict__ plo,
    const float* __restrict__ g,
    const unsigned short* __restrict__ S2hi, const unsigned short* __restrict__ S2lo,
    const unsigned short* __restrict__ vt, const unsigned short* __restrict__ vtlo,
    float* __restrict__ o)
{
  __shared__ unsigned short gh_lds[64*72];
  __shared__ unsigned short gl_lds[64*72];
  __shared__ unsigned short Mh_lds[64*72];
  __shared__ unsigned short Ml_lds[64*72];
  int n=blockIdx.x, h=blockIdx.y, b=blockIdx.z;
  int tid=threadIdx.x, lane=tid&63, w=tid>>6;
  int quad=lane>>4, lq=lane&15;
  int t0=n*64, bh=b*H_+h, strip=w*16;

  {
    int gu = tid>>2, gs0 = (tid&3)*16;
    const float* gr = g + ((size_t)(b*T_+t0+gu))*256 + h*64 + gs0;
    union{ unsigned short u[16]; bf16x8 v[2]; } GH, GL;
    #pragma unroll
    for(int j=0;j<16;j++) split2(gr[j], GH.u[j], GL.u[j]);
    *(bf16x8*)(void*)&gh_lds[gu*72+gs0]   = GH.v[0];
    *(bf16x8*)(void*)&gh_lds[gu*72+gs0+8] = GH.v[1];
    *(bf16x8*)(void*)&gl_lds[gu*72+gs0]   = GL.v[0];
    *(bf16x8*)(void*)&gl_lds[gu*72+gs0+8] = GL.v[1];
  }
  __syncthreads();

  {
    const unsigned short* ph = phi + ((size_t)bh*T_ + t0 + strip + lq)*64;
    const unsigned short* pl = plo + ((size_t)bh*T_ + t0 + strip + lq)*64;
    f32x4 ma[4];
    #pragma unroll
    for(int nf=0;nf<4;nf++) ma[nf] = (f32x4){0.f,0.f,0.f,0.f};
    #pragma unroll
    for(int ks=0;ks<2;ks++){
      bf16x8 pfh = *(const bf16x8*)(const void*)(ph + ks*32 + quad*8);
      bf16x8 pfl = *(const bf16x8*)(const void*)(pl + ks*32 + quad*8);
      #pragma unroll
      for(int nf=0;nf<4;nf++){
        bf16x8 gH = *(const bf16x8*)(const void*)&gh_lds[(nf*16+lq)*72 + ks*32 + quad*8];
        bf16x8 gL = *(const bf16x8*)(const void*)&gl_lds[(nf*16+lq)*72 + ks*32 + quad*8];
        ma[nf] = __builtin_amdgcn_mfma_f32_16x16x32_bf16(pfh, gH, ma[nf], 0,0,0);
        ma[nf] = __builtin_amdgcn_mfma_f32_16x16x32_bf16(pfh, gL, ma[nf], 0,0,0);
        ma[nf] = __builtin_amdgcn_mfma_f32_16x16x32_bf16(pfl, gH, ma[nf], 0,0,0);
      }
    }
    #pragma unroll
    for(int nf=0;nf<4;nf++){
      int u = nf*16 + lq;
      #pragma unroll
      for(int i=0;i<4;i++){
        int trow = strip + quad*4 + i;
        float val = (u <= trow) ? ma[nf][i] : 0.f;
        unsigned short hh, ll;
        split2(val, hh, ll);
        Mh_lds[trow*72 + u] = hh;
        Ml_lds[trow*72 + u] = ll;
      }
    }
  }
  __syncthreads();

  f32x4 oacc[4][4];
  #pragma unroll
  for(int i=0;i<4;i++)
    #pragma unroll
    for(int j=0;j<4;j++) oacc[i][j] = (f32x4){0.f,0.f,0.f,0.f};
  int c0 = w*64;
  size_t sgbase = ((size_t)bh*NC_ + n)*16384;
  #pragma unroll
  for(int ks=0;ks<2;ks++){
    bf16x8 pAh[4], pAl[4], mAh[4], mAl[4];
    #pragma unroll
    for(int mi=0;mi<4;mi++){
      size_t po = ((size_t)bh*T_ + t0 + mi*16+lq)*64 + ks*32 + quad*8;
      pAh[mi] = *(const bf16x8*)(const void*)(phi + po);
      pAl[mi] = *(const bf16x8*)(const void*)(plo + po);
      mAh[mi] = *(const bf16x8*)(const void*)&Mh_lds[(mi*16+lq)*72 + ks*32 + quad*8];
      mAl[mi] = *(const bf16x8*)(const void*)&Ml_lds[(mi*16+lq)*72 + ks*32 + quad*8];
    }
    #pragma unroll
    for(int ni=0;ni<4;ni++){
      int c = c0 + ni*16 + lq;
      size_t so = sgbase + (size_t)c*64 + ks*32 + quad*8;
      bf16x8 sgH = *(const bf16x8*)(const void*)(S2hi + so);
      bf16x8 sgL = *(const bf16x8*)(const void*)(S2lo + so);
      size_t vo = ((size_t)(bh*256 + c))*T_ + t0 + ks*32 + quad*8;
      bf16x8 vH = *(const bf16x8*)(const void*)(vt + vo);
      bf16x8 vL = *(const bf16x8*)(const void*)(vtlo + vo);
      #pragma unroll
      for(int mi=0;mi<4;mi++){
        oacc[mi][ni] = __builtin_amdgcn_mfma_f32_16x16x32_bf16(pAh[mi], sgH, oacc[mi][ni], 0,0,0);
        oacc[mi][ni] = __builtin_amdgcn_mfma_f32_16x16x32_bf16(pAh[mi], sgL, oacc[mi][ni], 0,0,0);
        oacc[mi][ni] = __builtin_amdgcn_mfma_f32_16x16x32_bf16(pAl[mi], sgH, oacc[mi][ni], 0,0,0);
        oacc[mi][ni] = __builtin_amdgcn_mfma_f32_16x16x32_bf16(mAh[mi], vH, oacc[mi][ni], 0,0,0);
        oacc[mi][ni] = __builtin_amdgcn_mfma_f32_16x16x32_bf16(mAl[mi], vH, oacc[mi][ni], 0,0,0);
        oacc[mi][ni] = __builtin_amdgcn_mfma_f32_16x16x32_bf16(mAh[mi], vL, oacc[mi][ni], 0,0,0);
      }
    }
  }
  #pragma unroll
  for(int mi=0;mi<4;mi++)
    #pragma unroll
    for(int ni=0;ni<4;ni++)
      #pragma unroll
      for(int i=0;i<4;i++){
        int trow = mi*16 + quad*4 + i, c = c0 + ni*16 + lq;
        size_t oi = ((size_t)bh*T_ + t0 + trow)*256 + c;
        o[oi] += oacc[mi][ni][i];
      }
}

// ---------------- swish + rmsnorm, gather heads -> split bf16 hi/lo ----------------
__global__ void swish_rms_split_kernel(const float* __restrict__ o, const float* __restrict__ w,
                                       unsigned short* __restrict__ ohi, unsigned short* __restrict__ olo){
  int bt=blockIdx.x, tid=threadIdx.x;
  int b = bt >> 11, t = bt & 2047;
  float y[4]; float ss=0.f;
  #pragma unroll
  for(int hh=0;hh<4;hh++){
    float x = o[((size_t)(b*H_+hh)*T_ + t)*256 + tid];
    float yy = x / (1.f + expf(-x));
    y[hh]=yy; ss += yy*yy;
  }
  __shared__ float red[256];
  red[tid]=ss; __syncthreads();
  for(int s2=128;s2>0;s2>>=1){ if(tid<s2) red[tid]+=red[tid+s2]; __syncthreads(); }
  float r = rsqrtf(red[0]/1024.f + 1e-5f);
  #pragma unroll
  for(int hh=0;hh<4;hh++){
    unsigned short a,bq;
    split2(y[hh]*r*w[hh*256+tid], a, bq);
    ohi[(size_t)bt*1024 + hh*256 + tid] = a;
    olo[(size_t)bt*1024 + hh*256 + tid] = bq;
  }
}

extern "C" void kernel_launch(void* const* d_in, const int* in_sizes, int n_in,
                              void* d_out, int out_size, void* d_ws, size_t ws_size,
                              hipStream_t stream){
  const float* hidden = (const float*)d_in[0];
  const float* w_norm = (const float*)d_in[1];
  const float* Wq = (const float*)d_in[2];
  const float* Wk = (const float*)d_in[3];
  const float* Wv = (const float*)d_in[4];
  const float* Ws = (const float*)d_in[5];
  const float* Wg = (const float*)d_in[6];
  const float* Wo = (const float*)d_in[7];
  float* out = (float*)d_out;

  char* p = (char*)d_ws;
  auto alloc = [&](size_t bytes)->void*{ void* r = (void*)p; p += (bytes + 255) & ~(size_t)255; return r; };
  unsigned short* h_hi = (unsigned short*)alloc(8388608);   // (4096,1024) bf16; reused for o2_hi
  unsigned short* h_lo = (unsigned short*)alloc(8388608);   //               ; reused for o2_lo
  unsigned short* Wc_hi = (unsigned short*)alloc(11010048); // (5376,1024) bf16 [Wq;Wk;Ws;Wv;Wg;Wo]
  unsigned short* Wc_lo = (unsigned short*)alloc(11010048);
  unsigned short* vslot = (unsigned short*)alloc(16777216); // vtlo (8.39MB) + S2hi (8.39MB)
  float* g   = (float*)alloc(4194304);                      // (4096,256) f32 — kept alive for o_state
  float* P1  = (float*)alloc(16777216);                     // G^T@S chunks; o aliases after prefix_split
  float* P2  = (float*)alloc(16777216);                     // S1hi/S1lo early; G^T@V f32 mid
  float* sc  = (float*)alloc(4194304);                      // (8,2048,64)
  float* ps  = (float*)alloc(4194304);                      // GThi/GTlo early; phi/plo late
  unsigned short* qks = (unsigned short*)alloc(25165824);   // q|k|s bf16, 3x(4096,1024)
  unsigned short* vt  = (unsigned short*)alloc(8388608);    // V^T bf16 hi (8,256,2048)

  unsigned short* vtlo = vslot;                    // V^T bf16 lo
  unsigned short* S2hi = vslot + 4194304;          // SG prefix hi (c-major chunks)
  unsigned short* q_bf = qks;
  unsigned short* k_bf = qks + 4194304;
  unsigned short* s_bf = qks + 8388608;
  unsigned short* S2lo = s_bf;                     // s_bf dead after sc_state; S2lo born after
  float* o = P1;                                   // P1 dead after chunk_prefix_split
  unsigned short* S1hi = (unsigned short*)P2;      // consumed by sc_state before chunk_outer_vt writes P2
  unsigned short* S1lo = S1hi + 4194304;
  unsigned short* GThi = (unsigned short*)ps;      // consumed by chunk_outer_vt; then phi/plo overwrite
  unsigned short* GTlo = GThi + 1048576;
  unsigned short* phi  = (unsigned short*)ps;
  unsigned short* plo  = phi + 1048576;

  rmsnorm_split_kernel<<<4096,256,0,stream>>>(hidden, w_norm, h_hi, h_lo);
  wsplit_kernel<<<5376,256,0,stream>>>(Wq, Wk, Ws, Wv, Wg, Wo, Wc_hi, Wc_lo);
  gemm_bf16s<<<dim3(34,32),256,0,stream>>>(h_hi, h_lo, Wc_hi, Wc_lo,
                                           qks, vt, vtlo, g, nullptr, 0);
  softmax256_kernel<<<4096,256,0,stream>>>(g);
  dim3 gc(32,4,2);
  g_transpose_split_kernel<<<gc,256,0,stream>>>(g, GThi, GTlo);
  chunk_outer_mfma<<<gc,256,0,stream>>>(GThi, GTlo, s_bf, P1);           // P1 = G^T @ S (s-major)
  chunk_prefix_split_kernel<<<512,256,0,stream>>>(P1, S1hi, S1lo);
  sc_state_mfma<<<gc,256,0,stream>>>(q_bf, s_bf, S1hi, S1lo, GThi, GTlo, sc);
  chunk_outer_vt<<<gc,256,0,stream>>>(GThi, GTlo, vt, vtlo, P2);         // P2 = G^T @ V (c-major)
  chunk_prefix_split_kernel<<<512,256,0,stream>>>(P2, S2hi, S2lo);
  window_attn_mfma<<<gc,512,0,stream>>>(q_bf, k_bf, vt, sc, o, phi, plo);
  o_state_mfma<<<gc,256,0,stream>>>(phi, plo, g, S2hi, S2lo, vt, vtlo, o);
  swish_rms_split_kernel<<<4096,256,0,stream>>>(o, w_norm, h_hi, h_lo);
  gemm_bf16s<<<dim3(8,32),256,0,stream>>>(h_hi, h_lo, Wc_hi + (size_t)4352*1024, Wc_lo + (size_t)4352*1024,
                                          nullptr, nullptr, nullptr, nullptr, out, 1);
}

// Round 12
// 384.595 us; speedup vs baseline: 1.0466x; 1.0183x over previous
//
#include <hip/hip_runtime.h>
#include <stdint.h>

#define B_  2
#define T_  2048
#define D_  1024
#define H_  4
#define S_  64
#define W_  512
#define CK_ 256
#define NC_ 32      // T_/64 chunks

typedef __attribute__((ext_vector_type(8))) short bf16x8;
typedef __attribute__((ext_vector_type(4))) float f32x4;
typedef __attribute__((ext_vector_type(4))) unsigned short u16x4;

__device__ __forceinline__ float bf2f(unsigned short u){ return __uint_as_float(((unsigned int)u)<<16); }
__device__ __forceinline__ unsigned short f2bf(float f){
  unsigned int u = __float_as_uint(f);
  u += 0x7fffu + ((u>>16)&1u);
  return (unsigned short)(u>>16);
}
__device__ __forceinline__ void split2(float y, unsigned short& hi, unsigned short& lo){
  hi = f2bf(y);
  lo = f2bf(y - bf2f(hi));
}

// async global->LDS, 16B per lane; lds base must be wave-uniform (HW adds lane*16)
__device__ __forceinline__ void gl_lds16(const unsigned short* g, unsigned short* l){
  __builtin_amdgcn_global_load_lds(
      (const __attribute__((address_space(1))) unsigned int*)g,
      (__attribute__((address_space(3))) unsigned int*)l, 16, 0, 0);
}

// ---------------- RMSNorm: x(B*T,D) -> split bf16 hi/lo ----------------
__global__ void rmsnorm_split_kernel(const float* __restrict__ x, const float* __restrict__ w,
                                     unsigned short* __restrict__ ohi, unsigned short* __restrict__ olo){
  int row = blockIdx.x, tid = threadIdx.x;
  const float* xr = x + (size_t)row*D_;
  float v0=xr[tid], v1=xr[tid+256], v2=xr[tid+512], v3=xr[tid+768];
  __shared__ float red[256];
  red[tid] = v0*v0+v1*v1+v2*v2+v3*v3;
  __syncthreads();
  for(int s=128;s>0;s>>=1){ if(tid<s) red[tid]+=red[tid+s]; __syncthreads(); }
  float r = rsqrtf(red[0]/(float)D_ + 1e-5f);
  size_t base = (size_t)row*D_;
  float y0=v0*r*w[tid], y1=v1*r*w[tid+256], y2=v2*r*w[tid+512], y3=v3*r*w[tid+768];
  unsigned short hh, ll;
  split2(y0,hh,ll); ohi[base+tid]=hh;     olo[base+tid]=ll;
  split2(y1,hh,ll); ohi[base+tid+256]=hh; olo[base+tid+256]=ll;
  split2(y2,hh,ll); ohi[base+tid+512]=hh; olo[base+tid+512]=ll;
  split2(y3,hh,ll); ohi[base+tid+768]=hh; olo[base+tid+768]=ll;
}

// ---------------- weight concat + split: rows [Wq;Wk;Ws;Wv;Wg;Wo] ----------------
__global__ void wsplit_kernel(const float* __restrict__ Wq, const float* __restrict__ Wk,
                              const float* __restrict__ Ws, const float* __restrict__ Wv,
                              const float* __restrict__ Wg, const float* __restrict__ Wo,
                              unsigned short* __restrict__ whi, unsigned short* __restrict__ wlo){
  int row = blockIdx.x, tid = threadIdx.x;
  const float* src;
  if(row < 1024)      src = Wq + (size_t)row*1024;
  else if(row < 2048) src = Wk + (size_t)(row-1024)*1024;
  else if(row < 3072) src = Ws + (size_t)(row-2048)*1024;
  else if(row < 4096) src = Wv + (size_t)(row-3072)*1024;
  else if(row < 4352) src = Wg + (size_t)(row-4096)*1024;
  else                src = Wo + (size_t)(row-4352)*1024;
  f32x4 vv = *(const f32x4*)(src + tid*4);
  u16x4 hh, ll;
  #pragma unroll
  for(int j=0;j<4;j++){ unsigned short a,b; split2(vv[j],a,b); hh[j]=a; ll[j]=b; }
  *(u16x4*)(whi + (size_t)row*1024 + tid*4) = hh;
  *(u16x4*)(wlo + (size_t)row*1024 + tid*4) = ll;
}

// ---------------- split-bf16 MFMA GEMM: C[M,4352] = A[4096,1024] * Wcat^T ----------------
__global__ __launch_bounds__(256,2) void gemm_bf16s(
    const unsigned short* __restrict__ Ahi, const unsigned short* __restrict__ Alo,
    const unsigned short* __restrict__ Whi, const unsigned short* __restrict__ Wlo,
    unsigned short* __restrict__ qks, unsigned short* __restrict__ vt,
    unsigned short* __restrict__ vtlo, float* __restrict__ gout,
    float* __restrict__ Cf, int mode)
{
  __shared__ unsigned short Ah_s[128*64];
  __shared__ unsigned short Al_s[128*64];
  __shared__ unsigned short Bh_s[128*64];
  __shared__ unsigned short Bl_s[128*64];
  int tid = threadIdx.x;
  int lane = tid & 63, w = tid >> 6;
  int quad = lane >> 4, lq = lane & 15;
  int wr = w >> 1, wc = w & 1;
  int bid = blockIdx.y*gridDim.x + blockIdx.x;
  int row0, col0;
  if(mode == 0){
    int xcd = bid & 7, slot = bid >> 3;
    int rx = xcd & 3, cx = xcd >> 2;
    int sr = slot / 17, sc2 = slot % 17;
    row0 = (rx*8 + sr)*128;
    col0 = (cx*17 + sc2)*128;
  } else {
    int q8 = (gridDim.x*gridDim.y) >> 3;
    int wg = (bid & 7)*q8 + (bid >> 3);
    col0 = (wg % gridDim.x)*128;
    row0 = (wg / gridDim.x)*128;
  }

  int l8 = lane >> 3;
  int chk = lane & 7;

  f32x4 acc[4][4];
  #pragma unroll
  for(int i=0;i<4;i++)
    #pragma unroll
    for(int j=0;j<4;j++) acc[i][j] = (f32x4){0.f,0.f,0.f,0.f};

  for(int kt=0; kt<1024; kt+=64){
    __syncthreads();
    #pragma unroll
    for(int j=0;j<4;j++){
      int rl = w*32 + j*8 + l8;
      int sc = (chk ^ (rl & 7))*8;
      int lbase = (w*32 + j*8)*64;
      gl_lds16(Ahi + (size_t)(row0+rl)*1024 + kt + sc, Ah_s + lbase);
      gl_lds16(Alo + (size_t)(row0+rl)*1024 + kt + sc, Al_s + lbase);
      gl_lds16(Whi + (size_t)(col0+rl)*1024 + kt + sc, Bh_s + lbase);
      gl_lds16(Wlo + (size_t)(col0+rl)*1024 + kt + sc, Bl_s + lbase);
    }
    __syncthreads();
    #pragma unroll
    for(int ks=0;ks<2;ks++){
      bf16x8 afh[4], afl[4], bfh[4], bfl[4];
      #pragma unroll
      for(int i=0;i<4;i++){
        int Ra = wr*64+i*16+lq;
        int ca = ((ks*4+quad) ^ (Ra&7))*8;
        afh[i] = *(const bf16x8*)(const void*)(Ah_s + Ra*64 + ca);
        afl[i] = *(const bf16x8*)(const void*)(Al_s + Ra*64 + ca);
        int Rb = wc*64+i*16+lq;
        int cb = ((ks*4+quad) ^ (Rb&7))*8;
        bfh[i] = *(const bf16x8*)(const void*)(Bh_s + Rb*64 + cb);
        bfl[i] = *(const bf16x8*)(const void*)(Bl_s + Rb*64 + cb);
      }
      #pragma unroll
      for(int mi=0;mi<4;mi++)
        #pragma unroll
        for(int ni=0;ni<4;ni++){
          acc[mi][ni] = __builtin_amdgcn_mfma_f32_16x16x32_bf16(afh[mi], bfh[ni], acc[mi][ni], 0,0,0);
          acc[mi][ni] = __builtin_amdgcn_mfma_f32_16x16x32_bf16(afh[mi], bfl[ni], acc[mi][ni], 0,0,0);
          acc[mi][ni] = __builtin_amdgcn_mfma_f32_16x16x32_bf16(afl[mi], bfh[ni], acc[mi][ni], 0,0,0);
        }
    }
  }

  int rbase = row0 + wr*64, cbase = col0 + wc*64;
  if(mode == 1){
    #pragma unroll
    for(int mi=0;mi<4;mi++)
      #pragma unroll
      for(int ni=0;ni<4;ni++)
        #pragma unroll
        for(int i=0;i<4;i++)
          Cf[(size_t)(rbase+mi*16+quad*4+i)*1024 + cbase+ni*16+lq] = acc[mi][ni][i];
  } else if(col0 < 3072){
    unsigned short* dst = qks + (size_t)(col0>>10)*4194304;
    #pragma unroll
    for(int mi=0;mi<4;mi++)
      #pragma unroll
      for(int ni=0;ni<4;ni++)
        #pragma unroll
        for(int i=0;i<4;i++){
          int rr = rbase+mi*16+quad*4+i, cc = (cbase+ni*16+lq) & 1023;
          dst[(size_t)rr*1024 + cc] = f2bf(acc[mi][ni][i]);
        }
  } else if(col0 < 4096){
    #pragma unroll
    for(int mi=0;mi<4;mi++)
      #pragma unroll
      for(int ni=0;ni<4;ni++)
        #pragma unroll
        for(int i=0;i<4;i++){
          int rr = rbase+mi*16+quad*4+i, cl = (cbase+ni*16+lq) & 1023;
          unsigned short hh2, ll2;
          split2(acc[mi][ni][i], hh2, ll2);
          int hh = cl>>8, cv = cl&255, bb = rr>>11, tt = rr&2047;
          size_t ti = ((size_t)((bb*H_+hh)*256 + cv))*T_ + tt;
          vt[ti] = hh2;
          vtlo[ti] = ll2;
        }
  } else {
    #pragma unroll
    for(int mi=0;mi<4;mi++)
      #pragma unroll
      for(int ni=0;ni<4;ni++)
        #pragma unroll
        for(int i=0;i<4;i++){
          int rr = rbase+mi*16+quad*4+i, cl = cbase+ni*16+lq - 4096;
          gout[(size_t)rr*256 + cl] = acc[mi][ni][i];
        }
  }
}

// ---------------- softmax over 256 (in place), one row per block ----------------
__global__ void softmax256_kernel(float* __restrict__ g){
  int row = blockIdx.x, tid = threadIdx.x;
  float x = g[(size_t)row*256+tid];
  __shared__ float red[256];
  red[tid]=x; __syncthreads();
  for(int s=128;s>0;s>>=1){ if(tid<s) red[tid]=fmaxf(red[tid],red[tid+s]); __syncthreads(); }
  float m = red[0]; __syncthreads();
  float e = expf(x-m);
  red[tid]=e; __syncthreads();
  for(int s=128;s>0;s>>=1){ if(tid<s) red[tid]+=red[tid+s]; __syncthreads(); }
  g[(size_t)row*256+tid] = e/red[0];
}

// ---------------- chunk outer (S path): out[s][c] = sum_u G[u,s]*S[u,c] ----------------
__global__ __launch_bounds__(256,1) void chunk_outer_mfma(
    const unsigned short* __restrict__ gthi, const unsigned short* __restrict__ gtlo,
    const unsigned short* __restrict__ s_bf, float* __restrict__ out)
{
  __shared__ unsigned short xh_lds[256*72];
  int n=blockIdx.x, h=blockIdx.y, b=blockIdx.z;
  int tid=threadIdx.x, lane=tid&63, w=tid>>6;
  int quad=lane>>4, lq=lane&15;
  int t0=n*64, bh=b*H_+h;

  const unsigned short* sb = s_bf + (size_t)(b*T_+t0)*D_ + h*CK_ + tid;
  for(int p2=0;p2<8;p2++){
    union{ unsigned short u[8]; bf16x8 v8; } r8;
    #pragma unroll
    for(int j=0;j<8;j++)
      r8.u[j] = sb[(size_t)(p2*8+j)*D_];
    *(bf16x8*)(void*)&xh_lds[tid*72 + p2*8] = r8.v8;
  }
  __syncthreads();

  size_t gtbase = ((size_t)bh*NC_ + n)*64;
  f32x4 acc[4][4];
  #pragma unroll
  for(int i=0;i<4;i++)
    #pragma unroll
    for(int j=0;j<4;j++) acc[i][j] = (f32x4){0.f,0.f,0.f,0.f};

  #pragma unroll
  for(int ks=0; ks<2; ks++){
    bf16x8 ah[4], al[4], bh4[4];
    #pragma unroll
    for(int mi=0;mi<4;mi++){
      ah[mi] = *(const bf16x8*)(const void*)(gthi + (gtbase + mi*16+lq)*64 + ks*32 + quad*8);
      al[mi] = *(const bf16x8*)(const void*)(gtlo + (gtbase + mi*16+lq)*64 + ks*32 + quad*8);
    }
    #pragma unroll
    for(int ni=0;ni<4;ni++)
      bh4[ni] = *(const bf16x8*)(const void*)&xh_lds[(w*64+ni*16+lq)*72 + ks*32 + quad*8];
    #pragma unroll
    for(int mi=0;mi<4;mi++)
      #pragma unroll
      for(int ni=0;ni<4;ni++){
        acc[mi][ni] = __builtin_amdgcn_mfma_f32_16x16x32_bf16(ah[mi], bh4[ni], acc[mi][ni], 0,0,0);
        acc[mi][ni] = __builtin_amdgcn_mfma_f32_16x16x32_bf16(al[mi], bh4[ni], acc[mi][ni], 0,0,0);
      }
  }
  size_t obase = ((size_t)bh*NC_ + n)*16384;
  #pragma unroll
  for(int mi=0;mi<4;mi++)
    #pragma unroll
    for(int ni=0;ni<4;ni++)
      #pragma unroll
      for(int i=0;i<4;i++){
        int s = mi*16 + quad*4 + i, c = w*64 + ni*16 + lq;
        out[obase + (size_t)s*256 + c] = acc[mi][ni][i];
      }
}

// ---------------- chunk outer (V path): out[c][s] = sum_u G[u,s]*V[u,c] ----------------
__global__ __launch_bounds__(256,1) void chunk_outer_vt(
    const unsigned short* __restrict__ gthi, const unsigned short* __restrict__ gtlo,
    const unsigned short* __restrict__ vt, const unsigned short* __restrict__ vtlo,
    float* __restrict__ out)
{
  int n=blockIdx.x, h=blockIdx.y, b=blockIdx.z;
  int tid=threadIdx.x, lane=tid&63, w=tid>>6;
  int quad=lane>>4, lq=lane&15;
  int t0=n*64, bh=b*H_+h;
  size_t gtbase = ((size_t)bh*NC_ + n)*64;
  f32x4 acc[4][4];
  #pragma unroll
  for(int i=0;i<4;i++)
    #pragma unroll
    for(int j=0;j<4;j++) acc[i][j] = (f32x4){0.f,0.f,0.f,0.f};

  #pragma unroll
  for(int ks=0; ks<2; ks++){
    bf16x8 ah[4], al[4];
    #pragma unroll
    for(int mi=0;mi<4;mi++){
      ah[mi] = *(const bf16x8*)(const void*)(gthi + (gtbase + mi*16+lq)*64 + ks*32 + quad*8);
      al[mi] = *(const bf16x8*)(const void*)(gtlo + (gtbase + mi*16+lq)*64 + ks*32 + quad*8);
    }
    #pragma unroll
    for(int ni=0;ni<4;ni++){
      size_t vo = ((size_t)(bh*256 + w*64 + ni*16 + lq))*T_ + t0 + ks*32 + quad*8;
      bf16x8 vh = *(const bf16x8*)(const void*)(vt + vo);
      bf16x8 vl = *(const bf16x8*)(const void*)(vtlo + vo);
      #pragma unroll
      for(int mi=0;mi<4;mi++){
        acc[mi][ni] = __builtin_amdgcn_mfma_f32_16x16x32_bf16(ah[mi], vh, acc[mi][ni], 0,0,0);
        acc[mi][ni] = __builtin_amdgcn_mfma_f32_16x16x32_bf16(al[mi], vh, acc[mi][ni], 0,0,0);
        acc[mi][ni] = __builtin_amdgcn_mfma_f32_16x16x32_bf16(ah[mi], vl, acc[mi][ni], 0,0,0);
      }
    }
  }
  size_t obase = ((size_t)bh*NC_ + n)*16384;
  #pragma unroll
  for(int mi=0;mi<4;mi++)
    #pragma unroll
    for(int ni=0;ni<4;ni++){
      int c = w*64 + ni*16 + lq, s0 = mi*16 + quad*4;
      *(f32x4*)&out[obase + (size_t)c*64 + s0] = acc[mi][ni];
    }
}

// ---------------- exclusive prefix over chunks -> split bf16 hi/lo ----------------
__global__ void chunk_prefix_split_kernel(const float* __restrict__ arr,
    unsigned short* __restrict__ hi, unsigned short* __restrict__ lo){
  int idx = blockIdx.x*256 + threadIdx.x;
  int bh = idx >> 14, e = idx & 16383;
  float run = 0.f;
  size_t base = (size_t)bh*NC_*16384 + e;
  for(int n=0;n<NC_;n++){
    size_t a = base + (size_t)n*16384;
    float t = arr[a];
    unsigned short hh, ll;
    split2(run, hh, ll);
    hi[a] = hh; lo[a] = ll;
    run += t;
  }
}

// ---------------- g (B*T,256) -> GT[bh*NC+n][s][u] split bf16 hi/lo ----------------
__global__ __launch_bounds__(256) void g_transpose_split_kernel(const float* __restrict__ g,
    unsigned short* __restrict__ gthi, unsigned short* __restrict__ gtlo){
  int n=blockIdx.x, h=blockIdx.y, b=blockIdx.z;
  int tid=threadIdx.x, t0=n*64;
  __shared__ float tt[64][65];
  #pragma unroll
  for(int p=0;p<16;p++){
    int u = (tid>>6) + p*4, s = tid&63;
    tt[s][u] = g[((size_t)(b*T_ + t0 + u))*256 + h*64 + s];
  }
  __syncthreads();
  size_t base = ((size_t)(b*H_+h)*NC_ + n)*64;
  #pragma unroll
  for(int p=0;p<16;p++){
    int s = (tid>>6) + p*4, u = tid&63;
    unsigned short hh, ll;
    split2(tt[s][u], hh, ll);
    gthi[(base+s)*64 + u] = hh;
    gtlo[(base+s)*64 + u] = ll;
  }
}

// ---------------- sc_state via MFMA (split-bf16, fp32-class numerics) ----------------
__global__ __launch_bounds__(256,1) void sc_state_mfma(
    const unsigned short* __restrict__ q_bf,
    const unsigned short* __restrict__ s_bf,
    const unsigned short* __restrict__ S1hi, const unsigned short* __restrict__ S1lo,
    const unsigned short* __restrict__ gthi, const unsigned short* __restrict__ gtlo,
    float* __restrict__ sc_state)
{
  int n=blockIdx.x, h=blockIdx.y, b=blockIdx.z;
  int tid=threadIdx.x, lane=tid&63, w=tid>>6;
  int quad=lane>>4, lq=lane&15;
  int t0=n*64, bh=b*H_+h, strip=w*16;

  __shared__ unsigned short A_hi[64*72];
  __shared__ unsigned short A_lo[64*72];

  bf16x8 qf[8];
  const unsigned short* qrow = q_bf + ((size_t)(b*T_ + t0 + strip + lq))*D_ + h*CK_ + quad*8;
  #pragma unroll
  for(int ks=0;ks<8;ks++) qf[ks] = *(const bf16x8*)(const void*)(qrow + ks*32);

  const unsigned short* sbase = s_bf + ((size_t)(b*T_ + t0))*D_ + h*CK_;
  f32x4 a1[4];
  #pragma unroll
  for(int nf=0;nf<4;nf++) a1[nf] = (f32x4){0.f,0.f,0.f,0.f};
  #pragma unroll
  for(int ks=0;ks<8;ks++){
    #pragma unroll
    for(int nf=0;nf<4;nf++){
      bf16x8 sf = *(const bf16x8*)(const void*)(sbase + (size_t)(nf*16+lq)*D_ + ks*32 + quad*8);
      a1[nf] = __builtin_amdgcn_mfma_f32_16x16x32_bf16(qf[ks], sf, a1[nf], 0,0,0);
    }
  }
  #pragma unroll
  for(int nf=0;nf<4;nf++){
    int u = nf*16 + lq;
    #pragma unroll
    for(int i=0;i<4;i++){
      int trow = strip + quad*4 + i;
      float val = (u <= trow) ? a1[nf][i] : 0.f;
      unsigned short hh, ll;
      split2(val, hh, ll);
      A_hi[trow*72 + u] = hh;
      A_lo[trow*72 + u] = ll;
    }
  }
  __syncthreads();

  bf16x8 afh[2], afl[2];
  #pragma unroll
  for(int ks=0;ks<2;ks++){
    afh[ks] = *(const bf16x8*)(const void*)&A_hi[(strip+lq)*72 + ks*32 + quad*8];
    afl[ks] = *(const bf16x8*)(const void*)&A_lo[(strip+lq)*72 + ks*32 + quad*8];
  }

  size_t s1base = ((size_t)bh*NC_ + n)*16384;
  size_t gtbase = ((size_t)bh*NC_ + n)*64;
  f32x4 acc2[4];
  #pragma unroll
  for(int nf=0;nf<4;nf++) acc2[nf] = (f32x4){0.f,0.f,0.f,0.f};
  #pragma unroll
  for(int ks=0;ks<8;ks++){
    #pragma unroll
    for(int nf=0;nf<4;nf++){
      size_t off = s1base + (size_t)(nf*16+lq)*256 + ks*32 + quad*8;
      bf16x8 b1 = *(const bf16x8*)(const void*)(S1hi + off);
      acc2[nf] = __builtin_amdgcn_mfma_f32_16x16x32_bf16(qf[ks], b1, acc2[nf], 0,0,0);
      bf16x8 b2 = *(const bf16x8*)(const void*)(S1lo + off);
      acc2[nf] = __builtin_amdgcn_mfma_f32_16x16x32_bf16(qf[ks], b2, acc2[nf], 0,0,0);
    }
  }
  #pragma unroll
  for(int ks=0;ks<2;ks++){
    #pragma unroll
    for(int nf=0;nf<4;nf++){
      size_t off = (gtbase + nf*16+lq)*64 + ks*32 + quad*8;
      bf16x8 gh = *(const bf16x8*)(const void*)(gthi + off);
      bf16x8 gl = *(const bf16x8*)(const void*)(gtlo + off);
      acc2[nf] = __builtin_amdgcn_mfma_f32_16x16x32_bf16(afh[ks], gh, acc2[nf], 0,0,0);
      acc2[nf] = __builtin_amdgcn_mfma_f32_16x16x32_bf16(afh[ks], gl, acc2[nf], 0,0,0);
      acc2[nf] = __builtin_amdgcn_mfma_f32_16x16x32_bf16(afl[ks], gh, acc2[nf], 0,0,0);
    }
  }
  #pragma unroll
  for(int nf=0;nf<4;nf++){
    #pragma unroll
    for(int i=0;i<4;i++){
      int trow = strip + quad*4 + i;
      sc_state[((size_t)bh*T_ + t0 + trow)*64 + nf*16+lq] = acc2[nf][i];
    }
  }
}

// ---------------- MFMA fused window attention + joint softmax ----------------
// Round-9 structure (256 threads, staging once) + K-tile register prefetch:
// K(jt+1) global loads issue right after the staging barrier and complete
// under the QK^T phase; loop-top writes kpre->LDS with no global on the path.
__global__ __launch_bounds__(256,1) void window_attn_mfma(
    const unsigned short* __restrict__ q_bf,
    const unsigned short* __restrict__ k_bf,
    const unsigned short* __restrict__ vt_bf,
    const float* __restrict__ sc_state,
    float* __restrict__ o,
    unsigned short* __restrict__ phi, unsigned short* __restrict__ plo)
{
  int nt=blockIdx.x, h=blockIdx.y, b=blockIdx.z;
  int tid=threadIdx.x;
  int lane = tid & 63, w = tid >> 6;
  int quad = lane >> 4, lq = lane & 15;
  int sp = w >> 1, np = w & 1;
  int t0 = nt*64, bh = b*H_ + h;
  float slope = exp2f(-2.0f*(float)h);

  __shared__ unsigned short kv_lds[256*72];
  __shared__ float S_lds[64*68];
  __shared__ unsigned short P_lds[64*72];
  __shared__ float m_lds[64], l_lds[64], al_lds[64];

  bf16x8 qf[2][8];
  #pragma unroll
  for(int st=0; st<2; st++){
    const unsigned short* qrow = q_bf + ((size_t)(b*T_ + t0 + 32*sp + 16*st + lq))*D_ + h*CK_ + quad*8;
    #pragma unroll
    for(int ks=0; ks<8; ks++)
      qf[st][ks] = *(const bf16x8*)(const void*)(qrow + ks*32);
  }

  int jt0 = (nt>=8)? nt-8 : 0;
  int krow = tid>>2, kseg = tid&3;
  bf16x8 kpre[8];
  {
    const unsigned short* src = k_bf + ((size_t)(b*T_ + jt0*64 + krow))*D_ + h*CK_ + kseg*64;
    #pragma unroll
    for(int i=0;i<8;i++) kpre[i] = *(const bf16x8*)(const void*)(src + i*8);
  }

  int r = tid >> 2, part = tid & 3;
  {
    const float* scrow = sc_state + ((size_t)bh*T_ + t0 + r)*64 + part*16;
    float pm = -1e30f, sv[16];
    #pragma unroll
    for(int i=0;i<16;i++){ sv[i] = scrow[i]; pm = fmaxf(pm, sv[i]); }
    pm = fmaxf(pm, __shfl_xor(pm,1)); pm = fmaxf(pm, __shfl_xor(pm,2));
    float ps = 0.f;
    #pragma unroll
    for(int i=0;i<16;i++) ps += __expf(sv[i]-pm);
    ps += __shfl_xor(ps,1); ps += __shfl_xor(ps,2);
    if(part==0){ m_lds[r]=pm; l_lds[r]=ps; }
  }

  f32x4 o_acc[2][8];
  #pragma unroll
  for(int st=0;st<2;st++)
    #pragma unroll
    for(int nv=0;nv<8;nv++) o_acc[st][nv] = (f32x4){0.f,0.f,0.f,0.f};
  __syncthreads();

  for(int jt=jt0; jt<=nt; jt++){
    int j0 = jt*64;
    {
      unsigned short* dst = kv_lds + krow*260 + kseg*64;
      #pragma unroll
      for(int i=0;i<8;i++) *(bf16x8*)(void*)(dst + i*8) = kpre[i];
    }
    __syncthreads();
    // prefetch next K tile into regs; completes under QK^T + S-write
    if(jt < nt){
      const unsigned short* src = k_bf + ((size_t)(b*T_ + j0 + 64 + krow))*D_ + h*CK_ + kseg*64;
      #pragma unroll
      for(int i=0;i<8;i++) kpre[i] = *(const bf16x8*)(const void*)(src + i*8);
    }
    f32x4 sacc[2][2];
    #pragma unroll
    for(int st=0;st<2;st++)
      #pragma unroll
      for(int n2=0;n2<2;n2++) sacc[st][n2] = (f32x4){0.f,0.f,0.f,0.f};
    #pragma unroll
    for(int n2=0;n2<2;n2++){
      int n = np*2 + n2;
      #pragma unroll
      for(int ks=0;ks<8;ks++){
        bf16x8 kf = *(const bf16x8*)(const void*)(kv_lds + (n*16+lq)*260 + ks*32 + quad*8);
        sacc[0][n2] = __builtin_amdgcn_mfma_f32_16x16x32_bf16(qf[0][ks], kf, sacc[0][n2], 0,0,0);
        sacc[1][n2] = __builtin_amdgcn_mfma_f32_16x16x32_bf16(qf[1][ks], kf, sacc[1][n2], 0,0,0);
      }
    }
    #pragma unroll
    for(int st=0;st<2;st++){
      #pragma unroll
      for(int n2=0;n2<2;n2++){
        int n = np*2+n2;
        int u = j0 + n*16 + lq;
        #pragma unroll
        for(int i=0;i<4;i++){
          int row = 32*sp + 16*st + quad*4 + i;
          int d = (t0 + row) - u;
          float val = (d>=0 && d<W_) ? sacc[st][n2][i] - slope*(float)d : -1e30f;
          S_lds[row*68 + n*16+lq] = val;
        }
      }
    }
    __syncthreads();
    {
      float s16[16], tm = -1e30f;
      #pragma unroll
      for(int i=0;i<16;i++){ s16[i] = S_lds[r*68 + part*16 + i]; tm = fmaxf(tm, s16[i]); }
      tm = fmaxf(tm, __shfl_xor(tm,1)); tm = fmaxf(tm, __shfl_xor(tm,2));
      float m_old = m_lds[r];
      float m_new = fmaxf(m_old, tm);
      float alpha = __expf(m_old - m_new);
      float ts = 0.f;
      union { unsigned short u[16]; bf16x8 v[2]; } pk;
      #pragma unroll
      for(int i=0;i<16;i++){ float p = __expf(s16[i]-m_new); ts += p; pk.u[i] = f2bf(p); }
      ts += __shfl_xor(ts,1); ts += __shfl_xor(ts,2);
      *(bf16x8*)(void*)&P_lds[r*72 + part*16]     = pk.v[0];
      *(bf16x8*)(void*)&P_lds[r*72 + part*16 + 8] = pk.v[1];
      if(part==0){ m_lds[r] = m_new; l_lds[r] = l_lds[r]*alpha + ts; al_lds[r] = alpha; }
      #pragma unroll
      for(int pass=0; pass<4; pass++){
        int cv = (tid>>2) + 64*pass, useg = (tid&3)*16;
        const unsigned short* src = vt_bf + ((size_t)(bh*256 + cv))*T_ + j0 + useg;
        unsigned short* dst = kv_lds + cv*72 + useg;
        *(bf16x8*)(void*)(dst)   = *(const bf16x8*)(const void*)(src);
        *(bf16x8*)(void*)(dst+8) = *(const bf16x8*)(const void*)(src+8);
      }
    }
    __syncthreads();
    #pragma unroll
    for(int st=0;st<2;st++){
      #pragma unroll
      for(int i=0;i<4;i++){
        float al = al_lds[32*sp+16*st+quad*4+i];
        #pragma unroll
        for(int nv=0;nv<8;nv++) o_acc[st][nv][i] *= al;
      }
    }
    bf16x8 pa[2][2];
    #pragma unroll
    for(int st=0;st<2;st++)
      #pragma unroll
      for(int k2=0;k2<2;k2++)
        pa[st][k2] = *(const bf16x8*)(const void*)&P_lds[(32*sp+16*st+lq)*72 + k2*32 + quad*8];
    #pragma unroll
    for(int nv=0;nv<8;nv++){
      int cvt = np*8 + nv;
      #pragma unroll
      for(int k2=0;k2<2;k2++){
        bf16x8 vb = *(const bf16x8*)(const void*)(kv_lds + (cvt*16+lq)*72 + k2*32 + quad*8);
        o_acc[0][nv] = __builtin_amdgcn_mfma_f32_16x16x32_bf16(pa[0][k2], vb, o_acc[0][nv], 0,0,0);
        o_acc[1][nv] = __builtin_amdgcn_mfma_f32_16x16x32_bf16(pa[1][k2], vb, o_acc[1][nv], 0,0,0);
      }
    }
    __syncthreads();
  }
  #pragma unroll
  for(int st=0;st<2;st++){
    #pragma unroll
    for(int i=0;i<4;i++){
      int row = 32*sp+16*st+quad*4+i;
      float rl = 1.0f / l_lds[row];
      #pragma unroll
      for(int nv=0;nv<8;nv++){
        int cv = (np*8+nv)*16 + lq;
        o[((size_t)bh*T_ + t0 + row)*256 + cv] = o_acc[st][nv][i] * rl;
      }
    }
  }
  {
    float mf = m_lds[r], rlf = 1.0f / l_lds[r];
    const float* scrow = sc_state + ((size_t)bh*T_ + t0 + r)*64 + part*16;
    size_t pb = ((size_t)bh*T_ + t0 + r)*64 + part*16;
    #pragma unroll
    for(int i=0;i<16;i++){
      float pv = __expf(scrow[i]-mf)*rlf;
      unsigned short hh, ll;
      split2(pv, hh, ll);
      phi[pb+i] = hh;
      plo[pb+i] = ll;
    }
  }
}

// ---------------- o += p @ SG + tril(p·g^T) @ V via MFMA ----------------
__global__ __launch_bounds__(256,1) void o_state_mfma(
    const unsigned short* __restrict__ phi, const unsigned short* __restrict__ plo,
    const float* __restrict__ g,
    const unsigned short* __restrict__ S2hi, const unsigned short* __restrict__ S2lo,
    const unsigned short* __restrict__ vt, const unsigned short* __restrict__ vtlo,
    float* __restrict__ o)
{
  __shared__ unsigned short gh_lds[64*72];
  __shared__ unsigned short gl_lds[64*72];
  __shared__ unsigned short Mh_lds[64*72];
  __shared__ unsigned short Ml_lds[64*72];
  int n=blockIdx.x, h=blockIdx.y, b=blockIdx.z;
  int tid=threadIdx.x, lane=tid&63, w=tid>>6;
  int quad=lane>>4, lq=lane&15;
  int t0=n*64, bh=b*H_+h, strip=w*16;

  {
    int gu = tid>>2, gs0 = (tid&3)*16;
    const float* gr = g + ((size_t)(b*T_+t0+gu))*256 + h*64 + gs0;
    union{ unsigned short u[16]; bf16x8 v[2]; } GH, GL;
    #pragma unroll
    for(int j=0;j<16;j++) split2(gr[j], GH.u[j], GL.u[j]);
    *(bf16x8*)(void*)&gh_lds[gu*72+gs0]   = GH.v[0];
    *(bf16x8*)(void*)&gh_lds[gu*72+gs0+8] = GH.v[1];
    *(bf16x8*)(void*)&gl_lds[gu*72+gs0]   = GL.v[0];
    *(bf16x8*)(void*)&gl_lds[gu*72+gs0+8] = GL.v[1];
  }
  __syncthreads();

  {
    const unsigned short* ph = phi + ((size_t)bh*T_ + t0 + strip + lq)*64;
    const unsigned short* pl = plo + ((size_t)bh*T_ + t0 + strip + lq)*64;
    f32x4 ma[4];
    #pragma unroll
    for(int nf=0;nf<4;nf++) ma[nf] = (f32x4){0.f,0.f,0.f,0.f};
    #pragma unroll
    for(int ks=0;ks<2;ks++){
      bf16x8 pfh = *(const bf16x8*)(const void*)(ph + ks*32 + quad*8);
      bf16x8 pfl = *(const bf16x8*)(const void*)(pl + ks*32 + quad*8);
      #pragma unroll
      for(int nf=0;nf<4;nf++){
        bf16x8 gH = *(const bf16x8*)(const void*)&gh_lds[(nf*16+lq)*72 + ks*32 + quad*8];
        bf16x8 gL = *(const bf16x8*)(const void*)&gl_lds[(nf*16+lq)*72 + ks*32 + quad*8];
        ma[nf] = __builtin_amdgcn_mfma_f32_16x16x32_bf16(pfh, gH, ma[nf], 0,0,0);
        ma[nf] = __builtin_amdgcn_mfma_f32_16x16x32_bf16(pfh, gL, ma[nf], 0,0,0);
        ma[nf] = __builtin_amdgcn_mfma_f32_16x16x32_bf16(pfl, gH, ma[nf], 0,0,0);
      }
    }
    #pragma unroll
    for(int nf=0;nf<4;nf++){
      int u = nf*16 + lq;
      #pragma unroll
      for(int i=0;i<4;i++){
        int trow = strip + quad*4 + i;
        float val = (u <= trow) ? ma[nf][i] : 0.f;
        unsigned short hh, ll;
        split2(val, hh, ll);
        Mh_lds[trow*72 + u] = hh;
        Ml_lds[trow*72 + u] = ll;
      }
    }
  }
  __syncthreads();

  f32x4 oacc[4][4];
  #pragma unroll
  for(int i=0;i<4;i++)
    #pragma unroll
    for(int j=0;j<4;j++) oacc[i][j] = (f32x4){0.f,0.f,0.f,0.f};
  int c0 = w*64;
  size_t sgbase = ((size_t)bh*NC_ + n)*16384;
  #pragma unroll
  for(int ks=0;ks<2;ks++){
    bf16x8 pAh[4], pAl[4], mAh[4], mAl[4];
    #pragma unroll
    for(int mi=0;mi<4;mi++){
      size_t po = ((size_t)bh*T_ + t0 + mi*16+lq)*64 + ks*32 + quad*8;
      pAh[mi] = *(const bf16x8*)(const void*)(phi + po);
      pAl[mi] = *(const bf16x8*)(const void*)(plo + po);
      mAh[mi] = *(const bf16x8*)(const void*)&Mh_lds[(mi*16+lq)*72 + ks*32 + quad*8];
      mAl[mi] = *(const bf16x8*)(const void*)&Ml_lds[(mi*16+lq)*72 + ks*32 + quad*8];
    }
    #pragma unroll
    for(int ni=0;ni<4;ni++){
      int c = c0 + ni*16 + lq;
      size_t so = sgbase + (size_t)c*64 + ks*32 + quad*8;
      bf16x8 sgH = *(const bf16x8*)(const void*)(S2hi + so);
      bf16x8 sgL = *(const bf16x8*)(const void*)(S2lo + so);
      size_t vo = ((size_t)(bh*256 + c))*T_ + t0 + ks*32 + quad*8;
      bf16x8 vH = *(const bf16x8*)(const void*)(vt + vo);
      bf16x8 vL = *(const bf16x8*)(const void*)(vtlo + vo);
      #pragma unroll
      for(int mi=0;mi<4;mi++){
        oacc[mi][ni] = __builtin_amdgcn_mfma_f32_16x16x32_bf16(pAh[mi], sgH, oacc[mi][ni], 0,0,0);
        oacc[mi][ni] = __builtin_amdgcn_mfma_f32_16x16x32_bf16(pAh[mi], sgL, oacc[mi][ni], 0,0,0);
        oacc[mi][ni] = __builtin_amdgcn_mfma_f32_16x16x32_bf16(pAl[mi], sgH, oacc[mi][ni], 0,0,0);
        oacc[mi][ni] = __builtin_amdgcn_mfma_f32_16x16x32_bf16(mAh[mi], vH, oacc[mi][ni], 0,0,0);
        oacc[mi][ni] = __builtin_amdgcn_mfma_f32_16x16x32_bf16(mAl[mi], vH, oacc[mi][ni], 0,0,0);
        oacc[mi][ni] = __builtin_amdgcn_mfma_f32_16x16x32_bf16(mAh[mi], vL, oacc[mi][ni], 0,0,0);
      }
    }
  }
  #pragma unroll
  for(int mi=0;mi<4;mi++)
    #pragma unroll
    for(int ni=0;ni<4;ni++)
      #pragma unroll
      for(int i=0;i<4;i++){
        int trow = mi*16 + quad*4 + i, c = c0 + ni*16 + lq;
        size_t oi = ((size_t)bh*T_ + t0 + trow)*256 + c;
        o[oi] += oacc[mi][ni][i];
      }
}

// ---------------- swish + rmsnorm, gather heads -> split bf16 hi/lo ----------------
__global__ void swish_rms_split_kernel(const float* __restrict__ o, const float* __restrict__ w,
                                       unsigned short* __restrict__ ohi, unsigned short* __restrict__ olo){
  int bt=blockIdx.x, tid=threadIdx.x;
  int b = bt >> 11, t = bt & 2047;
  float y[4]; float ss=0.f;
  #pragma unroll
  for(int hh=0;hh<4;hh++){
    float x = o[((size_t)(b*H_+hh)*T_ + t)*256 + tid];
    float yy = x / (1.f + expf(-x));
    y[hh]=yy; ss += yy*yy;
  }
  __shared__ float red[256];
  red[tid]=ss; __syncthreads();
  for(int s2=128;s2>0;s2>>=1){ if(tid<s2) red[tid]+=red[tid+s2]; __syncthreads(); }
  float r = rsqrtf(red[0]/1024.f + 1e-5f);
  #pragma unroll
  for(int hh=0;hh<4;hh++){
    unsigned short a,bq;
    split2(y[hh]*r*w[hh*256+tid], a, bq);
    ohi[(size_t)bt*1024 + hh*256 + tid] = a;
    olo[(size_t)bt*1024 + hh*256 + tid] = bq;
  }
}

extern "C" void kernel_launch(void* const* d_in, const int* in_sizes, int n_in,
                              void* d_out, int out_size, void* d_ws, size_t ws_size,
                              hipStream_t stream){
  const float* hidden = (const float*)d_in[0];
  const float* w_norm = (const float*)d_in[1];
  const float* Wq = (const float*)d_in[2];
  const float* Wk = (const float*)d_in[3];
  const float* Wv = (const float*)d_in[4];
  const float* Ws = (const float*)d_in[5];
  const float* Wg = (const float*)d_in[6];
  const float* Wo = (const float*)d_in[7];
  float* out = (float*)d_out;

  char* p = (char*)d_ws;
  auto alloc = [&](size_t bytes)->void*{ void* r = (void*)p; p += (bytes + 255) & ~(size_t)255; return r; };
  unsigned short* h_hi = (unsigned short*)alloc(8388608);   // (4096,1024) bf16; reused for o2_hi
  unsigned short* h_lo = (unsigned short*)alloc(8388608);   //               ; reused for o2_lo
  unsigned short* Wc_hi = (unsigned short*)alloc(11010048); // (5376,1024) bf16 [Wq;Wk;Ws;Wv;Wg;Wo]
  unsigned short* Wc_lo = (unsigned short*)alloc(11010048);
  unsigned short* vslot = (unsigned short*)alloc(16777216); // vtlo (8.39MB) + S2hi (8.39MB)
  float* g   = (float*)alloc(4194304);                      // (4096,256) f32 — kept alive for o_state
  float* P1  = (float*)alloc(16777216);                     // G^T@S chunks; o aliases after prefix_split
  float* P2  = (float*)alloc(16777216);                     // S1hi/S1lo early; G^T@V f32 mid
  float* sc  = (float*)alloc(4194304);                      // (8,2048,64)
  float* ps  = (float*)alloc(4194304);                      // GThi/GTlo early; phi/plo late
  unsigned short* qks = (unsigned short*)alloc(25165824);   // q|k|s bf16, 3x(4096,1024)
  unsigned short* vt  = (unsigned short*)alloc(8388608);    // V^T bf16 hi (8,256,2048)

  unsigned short* vtlo = vslot;                    // V^T bf16 lo
  unsigned short* S2hi = vslot + 4194304;          // SG prefix hi (c-major chunks)
  unsigned short* q_bf = qks;
  unsigned short* k_bf = qks + 4194304;
  unsigned short* s_bf = qks + 8388608;
  unsigned short* S2lo = s_bf;                     // s_bf dead after sc_state; S2lo born after
  float* o = P1;                                   // P1 dead after chunk_prefix_split
  unsigned short* S1hi = (unsigned short*)P2;      // consumed by sc_state before chunk_outer_vt writes P2
  unsigned short* S1lo = S1hi + 4194304;
  unsigned short* GThi = (unsigned short*)ps;      // consumed by chunk_outer_vt; then phi/plo overwrite
  unsigned short* GTlo = GThi + 1048576;
  unsigned short* phi  = (unsigned short*)ps;
  unsigned short* plo  = phi + 1048576;

  rmsnorm_split_kernel<<<4096,256,0,stream>>>(hidden, w_norm, h_hi, h_lo);
  wsplit_kernel<<<5376,256,0,stream>>>(Wq, Wk, Ws, Wv, Wg, Wo, Wc_hi, Wc_lo);
  gemm_bf16s<<<dim3(34,32),256,0,stream>>>(h_hi, h_lo, Wc_hi, Wc_lo,
                                           qks, vt, vtlo, g, nullptr, 0);
  softmax256_kernel<<<4096,256,0,stream>>>(g);
  dim3 gc(32,4,2);
  g_transpose_split_kernel<<<gc,256,0,stream>>>(g, GThi, GTlo);
  chunk_outer_mfma<<<gc,256,0,stream>>>(GThi, GTlo, s_bf, P1);           // P1 = G^T @ S (s-major)
  chunk_prefix_split_kernel<<<512,256,0,stream>>>(P1, S1hi, S1lo);
  sc_state_mfma<<<gc,256,0,stream>>>(q_bf, s_bf, S1hi, S1lo, GThi, GTlo, sc);
  chunk_outer_vt<<<gc,256,0,stream>>>(GThi, GTlo, vt, vtlo, P2);         // P2 = G^T @ V (c-major)
  chunk_prefix_split_kernel<<<512,256,0,stream>>>(P2, S2hi, S2lo);
  window_attn_mfma<<<gc,256,0,stream>>>(q_bf, k_bf, vt, sc, o, phi, plo);
  o_state_mfma<<<gc,256,0,stream>>>(phi, plo, g, S2hi, S2lo, vt, vtlo, o);
  swish_rms_split_kernel<<<4096,256,0,stream>>>(o, w_norm, h_hi, h_lo);
  gemm_bf16s<<<dim3(8,32),256,0,stream>>>(h_hi, h_lo, Wc_hi + (size_t)4352*1024, Wc_lo + (size_t)4352*1024,
                                          nullptr, nullptr, nullptr, nullptr, out, 1);
}

// Round 13
// 375.491 us; speedup vs baseline: 1.0720x; 1.0242x over previous
//
#include <hip/hip_runtime.h>
#include <stdint.h>

#define B_  2
#define T_  2048
#define D_  1024
#define H_  4
#define S_  64
#define W_  512
#define CK_ 256
#define NC_ 32      // T_/64 chunks

typedef __attribute__((ext_vector_type(8))) short bf16x8;
typedef __attribute__((ext_vector_type(4))) float f32x4;
typedef __attribute__((ext_vector_type(4))) unsigned short u16x4;

__device__ __forceinline__ float bf2f(unsigned short u){ return __uint_as_float(((unsigned int)u)<<16); }
__device__ __forceinline__ unsigned short f2bf(float f){
  unsigned int u = __float_as_uint(f);
  u += 0x7fffu + ((u>>16)&1u);
  return (unsigned short)(u>>16);
}
__device__ __forceinline__ void split2(float y, unsigned short& hi, unsigned short& lo){
  hi = f2bf(y);
  lo = f2bf(y - bf2f(hi));
}

// async global->LDS, 16B per lane; lds base must be wave-uniform (HW adds lane*16)
__device__ __forceinline__ void gl_lds16(const unsigned short* g, unsigned short* l){
  __builtin_amdgcn_global_load_lds(
      (const __attribute__((address_space(1))) unsigned int*)g,
      (__attribute__((address_space(3))) unsigned int*)l, 16, 0, 0);
}

// ---------------- fused: RMSNorm split (blocks 0..4095) + weight concat split ----------------
__global__ void norm_wsplit_kernel(const float* __restrict__ x, const float* __restrict__ w,
                                   unsigned short* __restrict__ ohi, unsigned short* __restrict__ olo,
                                   const float* __restrict__ Wq, const float* __restrict__ Wk,
                                   const float* __restrict__ Ws, const float* __restrict__ Wv,
                                   const float* __restrict__ Wg, const float* __restrict__ Wo,
                                   unsigned short* __restrict__ whi, unsigned short* __restrict__ wlo){
  int tid = threadIdx.x;
  if(blockIdx.x < 4096){
    int row = blockIdx.x;
    const float* xr = x + (size_t)row*D_;
    float v0=xr[tid], v1=xr[tid+256], v2=xr[tid+512], v3=xr[tid+768];
    __shared__ float red[256];
    red[tid] = v0*v0+v1*v1+v2*v2+v3*v3;
    __syncthreads();
    for(int s=128;s>0;s>>=1){ if(tid<s) red[tid]+=red[tid+s]; __syncthreads(); }
    float r = rsqrtf(red[0]/(float)D_ + 1e-5f);
    size_t base = (size_t)row*D_;
    float y0=v0*r*w[tid], y1=v1*r*w[tid+256], y2=v2*r*w[tid+512], y3=v3*r*w[tid+768];
    unsigned short hh, ll;
    split2(y0,hh,ll); ohi[base+tid]=hh;     olo[base+tid]=ll;
    split2(y1,hh,ll); ohi[base+tid+256]=hh; olo[base+tid+256]=ll;
    split2(y2,hh,ll); ohi[base+tid+512]=hh; olo[base+tid+512]=ll;
    split2(y3,hh,ll); ohi[base+tid+768]=hh; olo[base+tid+768]=ll;
  } else {
    int row = blockIdx.x - 4096;
    const float* src;
    if(row < 1024)      src = Wq + (size_t)row*1024;
    else if(row < 2048) src = Wk + (size_t)(row-1024)*1024;
    else if(row < 3072) src = Ws + (size_t)(row-2048)*1024;
    else if(row < 4096) src = Wv + (size_t)(row-3072)*1024;
    else if(row < 4352) src = Wg + (size_t)(row-4096)*1024;
    else                src = Wo + (size_t)(row-4352)*1024;
    f32x4 vv = *(const f32x4*)(src + tid*4);
    u16x4 hh, ll;
    #pragma unroll
    for(int j=0;j<4;j++){ unsigned short a,b2; split2(vv[j],a,b2); hh[j]=a; ll[j]=b2; }
    *(u16x4*)(whi + (size_t)row*1024 + tid*4) = hh;
    *(u16x4*)(wlo + (size_t)row*1024 + tid*4) = ll;
  }
}

// ---------------- split-bf16 MFMA GEMM: C[M,4352] = A[4096,1024] * Wcat^T ----------------
__global__ __launch_bounds__(256,2) void gemm_bf16s(
    const unsigned short* __restrict__ Ahi, const unsigned short* __restrict__ Alo,
    const unsigned short* __restrict__ Whi, const unsigned short* __restrict__ Wlo,
    unsigned short* __restrict__ qks, unsigned short* __restrict__ vt,
    unsigned short* __restrict__ vtlo, float* __restrict__ gout,
    float* __restrict__ Cf, int mode)
{
  __shared__ unsigned short Ah_s[128*64];
  __shared__ unsigned short Al_s[128*64];
  __shared__ unsigned short Bh_s[128*64];
  __shared__ unsigned short Bl_s[128*64];
  int tid = threadIdx.x;
  int lane = tid & 63, w = tid >> 6;
  int quad = lane >> 4, lq = lane & 15;
  int wr = w >> 1, wc = w & 1;
  int bid = blockIdx.y*gridDim.x + blockIdx.x;
  int row0, col0;
  if(mode == 0){
    int xcd = bid & 7, slot = bid >> 3;
    int rx = xcd & 3, cx = xcd >> 2;
    int sr = slot / 17, sc2 = slot % 17;
    row0 = (rx*8 + sr)*128;
    col0 = (cx*17 + sc2)*128;
  } else {
    int q8 = (gridDim.x*gridDim.y) >> 3;
    int wg = (bid & 7)*q8 + (bid >> 3);
    col0 = (wg % gridDim.x)*128;
    row0 = (wg / gridDim.x)*128;
  }

  int l8 = lane >> 3;
  int chk = lane & 7;

  f32x4 acc[4][4];
  #pragma unroll
  for(int i=0;i<4;i++)
    #pragma unroll
    for(int j=0;j<4;j++) acc[i][j] = (f32x4){0.f,0.f,0.f,0.f};

  for(int kt=0; kt<1024; kt+=64){
    __syncthreads();
    #pragma unroll
    for(int j=0;j<4;j++){
      int rl = w*32 + j*8 + l8;
      int sc = (chk ^ (rl & 7))*8;
      int lbase = (w*32 + j*8)*64;
      gl_lds16(Ahi + (size_t)(row0+rl)*1024 + kt + sc, Ah_s + lbase);
      gl_lds16(Alo + (size_t)(row0+rl)*1024 + kt + sc, Al_s + lbase);
      gl_lds16(Whi + (size_t)(col0+rl)*1024 + kt + sc, Bh_s + lbase);
      gl_lds16(Wlo + (size_t)(col0+rl)*1024 + kt + sc, Bl_s + lbase);
    }
    __syncthreads();
    #pragma unroll
    for(int ks=0;ks<2;ks++){
      bf16x8 afh[4], afl[4], bfh[4], bfl[4];
      #pragma unroll
      for(int i=0;i<4;i++){
        int Ra = wr*64+i*16+lq;
        int ca = ((ks*4+quad) ^ (Ra&7))*8;
        afh[i] = *(const bf16x8*)(const void*)(Ah_s + Ra*64 + ca);
        afl[i] = *(const bf16x8*)(const void*)(Al_s + Ra*64 + ca);
        int Rb = wc*64+i*16+lq;
        int cb = ((ks*4+quad) ^ (Rb&7))*8;
        bfh[i] = *(const bf16x8*)(const void*)(Bh_s + Rb*64 + cb);
        bfl[i] = *(const bf16x8*)(const void*)(Bl_s + Rb*64 + cb);
      }
      #pragma unroll
      for(int mi=0;mi<4;mi++)
        #pragma unroll
        for(int ni=0;ni<4;ni++){
          acc[mi][ni] = __builtin_amdgcn_mfma_f32_16x16x32_bf16(afh[mi], bfh[ni], acc[mi][ni], 0,0,0);
          acc[mi][ni] = __builtin_amdgcn_mfma_f32_16x16x32_bf16(afh[mi], bfl[ni], acc[mi][ni], 0,0,0);
          acc[mi][ni] = __builtin_amdgcn_mfma_f32_16x16x32_bf16(afl[mi], bfh[ni], acc[mi][ni], 0,0,0);
        }
    }
  }

  int rbase = row0 + wr*64, cbase = col0 + wc*64;
  if(mode == 1){
    #pragma unroll
    for(int mi=0;mi<4;mi++)
      #pragma unroll
      for(int ni=0;ni<4;ni++)
        #pragma unroll
        for(int i=0;i<4;i++)
          Cf[(size_t)(rbase+mi*16+quad*4+i)*1024 + cbase+ni*16+lq] = acc[mi][ni][i];
  } else if(col0 < 3072){
    unsigned short* dst = qks + (size_t)(col0>>10)*4194304;
    #pragma unroll
    for(int mi=0;mi<4;mi++)
      #pragma unroll
      for(int ni=0;ni<4;ni++)
        #pragma unroll
        for(int i=0;i<4;i++){
          int rr = rbase+mi*16+quad*4+i, cc = (cbase+ni*16+lq) & 1023;
          dst[(size_t)rr*1024 + cc] = f2bf(acc[mi][ni][i]);
        }
  } else if(col0 < 4096){
    #pragma unroll
    for(int mi=0;mi<4;mi++)
      #pragma unroll
      for(int ni=0;ni<4;ni++)
        #pragma unroll
        for(int i=0;i<4;i++){
          int rr = rbase+mi*16+quad*4+i, cl = (cbase+ni*16+lq) & 1023;
          unsigned short hh2, ll2;
          split2(acc[mi][ni][i], hh2, ll2);
          int hh = cl>>8, cv = cl&255, bb = rr>>11, tt = rr&2047;
          size_t ti = ((size_t)((bb*H_+hh)*256 + cv))*T_ + tt;
          vt[ti] = hh2;
          vtlo[ti] = ll2;
        }
  } else {
    #pragma unroll
    for(int mi=0;mi<4;mi++)
      #pragma unroll
      for(int ni=0;ni<4;ni++)
        #pragma unroll
        for(int i=0;i<4;i++){
          int rr = rbase+mi*16+quad*4+i, cl = cbase+ni*16+lq - 4096;
          gout[(size_t)rr*256 + cl] = acc[mi][ni][i];
        }
  }
}

// ---------------- softmax over 256 + fused transpose-split to GT ----------------
__global__ void softmax256_gt_kernel(float* __restrict__ g,
    unsigned short* __restrict__ gthi, unsigned short* __restrict__ gtlo){
  int row = blockIdx.x, tid = threadIdx.x;
  float x = g[(size_t)row*256+tid];
  __shared__ float red[256];
  red[tid]=x; __syncthreads();
  for(int s=128;s>0;s>>=1){ if(tid<s) red[tid]=fmaxf(red[tid],red[tid+s]); __syncthreads(); }
  float m = red[0]; __syncthreads();
  float e = expf(x-m);
  red[tid]=e; __syncthreads();
  for(int s=128;s>0;s>>=1){ if(tid<s) red[tid]+=red[tid+s]; __syncthreads(); }
  float val = e/red[0];
  g[(size_t)row*256+tid] = val;
  // GT[bh*NC+n][s][u]: row = b*T_+t, t = n*64+u; tid = hsel*64+s
  int b = row >> 11, t = row & 2047;
  int n = t >> 6, u = t & 63;
  int hsel = tid >> 6, s = tid & 63;
  unsigned short hh, ll;
  split2(val, hh, ll);
  size_t base = ((size_t)(b*H_+hsel)*NC_ + n)*64;
  gthi[(base+s)*64 + u] = hh;
  gtlo[(base+s)*64 + u] = ll;
}

// ---------------- fused chunk outer: P1[s][c] = G^T@S (2-term), P2f[c][s] = G^T@V (3-term) ----------------
__global__ __launch_bounds__(256,1) void chunk_outer_both(
    const unsigned short* __restrict__ gthi, const unsigned short* __restrict__ gtlo,
    const unsigned short* __restrict__ s_bf,
    const unsigned short* __restrict__ vt, const unsigned short* __restrict__ vtlo,
    float* __restrict__ outS, float* __restrict__ outV)
{
  __shared__ unsigned short xh_lds[256*72];
  int n=blockIdx.x, h=blockIdx.y, b=blockIdx.z;
  int tid=threadIdx.x, lane=tid&63, w=tid>>6;
  int quad=lane>>4, lq=lane&15;
  int t0=n*64, bh=b*H_+h;
  size_t gtbase = ((size_t)bh*NC_ + n)*64;
  size_t obase = ((size_t)bh*NC_ + n)*16384;

  // ---- S path ----
  const unsigned short* sb = s_bf + (size_t)(b*T_+t0)*D_ + h*CK_ + tid;
  for(int p2=0;p2<8;p2++){
    union{ unsigned short u[8]; bf16x8 v8; } r8;
    #pragma unroll
    for(int j=0;j<8;j++)
      r8.u[j] = sb[(size_t)(p2*8+j)*D_];
    *(bf16x8*)(void*)&xh_lds[tid*72 + p2*8] = r8.v8;
  }
  __syncthreads();

  f32x4 acc[4][4];
  #pragma unroll
  for(int i=0;i<4;i++)
    #pragma unroll
    for(int j=0;j<4;j++) acc[i][j] = (f32x4){0.f,0.f,0.f,0.f};
  #pragma unroll
  for(int ks=0; ks<2; ks++){
    bf16x8 ah[4], al[4], bh4[4];
    #pragma unroll
    for(int mi=0;mi<4;mi++){
      ah[mi] = *(const bf16x8*)(const void*)(gthi + (gtbase + mi*16+lq)*64 + ks*32 + quad*8);
      al[mi] = *(const bf16x8*)(const void*)(gtlo + (gtbase + mi*16+lq)*64 + ks*32 + quad*8);
    }
    #pragma unroll
    for(int ni=0;ni<4;ni++)
      bh4[ni] = *(const bf16x8*)(const void*)&xh_lds[(w*64+ni*16+lq)*72 + ks*32 + quad*8];
    #pragma unroll
    for(int mi=0;mi<4;mi++)
      #pragma unroll
      for(int ni=0;ni<4;ni++){
        acc[mi][ni] = __builtin_amdgcn_mfma_f32_16x16x32_bf16(ah[mi], bh4[ni], acc[mi][ni], 0,0,0);
        acc[mi][ni] = __builtin_amdgcn_mfma_f32_16x16x32_bf16(al[mi], bh4[ni], acc[mi][ni], 0,0,0);
      }
  }
  #pragma unroll
  for(int mi=0;mi<4;mi++)
    #pragma unroll
    for(int ni=0;ni<4;ni++)
      #pragma unroll
      for(int i=0;i<4;i++){
        int s = mi*16 + quad*4 + i, c = w*64 + ni*16 + lq;
        outS[obase + (size_t)s*256 + c] = acc[mi][ni][i];
      }

  // ---- V path (no barrier needed; independent of xh_lds) ----
  #pragma unroll
  for(int i=0;i<4;i++)
    #pragma unroll
    for(int j=0;j<4;j++) acc[i][j] = (f32x4){0.f,0.f,0.f,0.f};
  #pragma unroll
  for(int ks=0; ks<2; ks++){
    bf16x8 ah[4], al[4];
    #pragma unroll
    for(int mi=0;mi<4;mi++){
      ah[mi] = *(const bf16x8*)(const void*)(gthi + (gtbase + mi*16+lq)*64 + ks*32 + quad*8);
      al[mi] = *(const bf16x8*)(const void*)(gtlo + (gtbase + mi*16+lq)*64 + ks*32 + quad*8);
    }
    #pragma unroll
    for(int ni=0;ni<4;ni++){
      size_t vo = ((size_t)(bh*256 + w*64 + ni*16 + lq))*T_ + t0 + ks*32 + quad*8;
      bf16x8 vh = *(const bf16x8*)(const void*)(vt + vo);
      bf16x8 vl = *(const bf16x8*)(const void*)(vtlo + vo);
      #pragma unroll
      for(int mi=0;mi<4;mi++){
        acc[mi][ni] = __builtin_amdgcn_mfma_f32_16x16x32_bf16(ah[mi], vh, acc[mi][ni], 0,0,0);
        acc[mi][ni] = __builtin_amdgcn_mfma_f32_16x16x32_bf16(al[mi], vh, acc[mi][ni], 0,0,0);
        acc[mi][ni] = __builtin_amdgcn_mfma_f32_16x16x32_bf16(ah[mi], vl, acc[mi][ni], 0,0,0);
      }
    }
  }
  #pragma unroll
  for(int mi=0;mi<4;mi++)
    #pragma unroll
    for(int ni=0;ni<4;ni++){
      int c = w*64 + ni*16 + lq, s0 = mi*16 + quad*4;
      *(f32x4*)&outV[obase + (size_t)c*64 + s0] = acc[mi][ni];
    }
}

// ---------------- exclusive prefix over chunks -> split bf16 hi/lo ----------------
__global__ void chunk_prefix_split_kernel(const float* __restrict__ arr,
    unsigned short* __restrict__ hi, unsigned short* __restrict__ lo){
  int idx = blockIdx.x*256 + threadIdx.x;
  int bh = idx >> 14, e = idx & 16383;
  float run = 0.f;
  size_t base = (size_t)bh*NC_*16384 + e;
  for(int n=0;n<NC_;n++){
    size_t a = base + (size_t)n*16384;
    float t = arr[a];
    unsigned short hh, ll;
    split2(run, hh, ll);
    hi[a] = hh; lo[a] = ll;
    run += t;
  }
}

// ---------------- sc_state via MFMA (split-bf16, fp32-class numerics) ----------------
__global__ __launch_bounds__(256,1) void sc_state_mfma(
    const unsigned short* __restrict__ q_bf,
    const unsigned short* __restrict__ s_bf,
    const unsigned short* __restrict__ S1hi, const unsigned short* __restrict__ S1lo,
    const unsigned short* __restrict__ gthi, const unsigned short* __restrict__ gtlo,
    float* __restrict__ sc_state)
{
  int n=blockIdx.x, h=blockIdx.y, b=blockIdx.z;
  int tid=threadIdx.x, lane=tid&63, w=tid>>6;
  int quad=lane>>4, lq=lane&15;
  int t0=n*64, bh=b*H_+h, strip=w*16;

  __shared__ unsigned short A_hi[64*72];
  __shared__ unsigned short A_lo[64*72];

  bf16x8 qf[8];
  const unsigned short* qrow = q_bf + ((size_t)(b*T_ + t0 + strip + lq))*D_ + h*CK_ + quad*8;
  #pragma unroll
  for(int ks=0;ks<8;ks++) qf[ks] = *(const bf16x8*)(const void*)(qrow + ks*32);

  const unsigned short* sbase = s_bf + ((size_t)(b*T_ + t0))*D_ + h*CK_;
  f32x4 a1[4];
  #pragma unroll
  for(int nf=0;nf<4;nf++) a1[nf] = (f32x4){0.f,0.f,0.f,0.f};
  #pragma unroll
  for(int ks=0;ks<8;ks++){
    #pragma unroll
    for(int nf=0;nf<4;nf++){
      bf16x8 sf = *(const bf16x8*)(const void*)(sbase + (size_t)(nf*16+lq)*D_ + ks*32 + quad*8);
      a1[nf] = __builtin_amdgcn_mfma_f32_16x16x32_bf16(qf[ks], sf, a1[nf], 0,0,0);
    }
  }
  #pragma unroll
  for(int nf=0;nf<4;nf++){
    int u = nf*16 + lq;
    #pragma unroll
    for(int i=0;i<4;i++){
      int trow = strip + quad*4 + i;
      float val = (u <= trow) ? a1[nf][i] : 0.f;
      unsigned short hh, ll;
      split2(val, hh, ll);
      A_hi[trow*72 + u] = hh;
      A_lo[trow*72 + u] = ll;
    }
  }
  __syncthreads();

  bf16x8 afh[2], afl[2];
  #pragma unroll
  for(int ks=0;ks<2;ks++){
    afh[ks] = *(const bf16x8*)(const void*)&A_hi[(strip+lq)*72 + ks*32 + quad*8];
    afl[ks] = *(const bf16x8*)(const void*)&A_lo[(strip+lq)*72 + ks*32 + quad*8];
  }

  size_t s1base = ((size_t)bh*NC_ + n)*16384;
  size_t gtbase = ((size_t)bh*NC_ + n)*64;
  f32x4 acc2[4];
  #pragma unroll
  for(int nf=0;nf<4;nf++) acc2[nf] = (f32x4){0.f,0.f,0.f,0.f};
  #pragma unroll
  for(int ks=0;ks<8;ks++){
    #pragma unroll
    for(int nf=0;nf<4;nf++){
      size_t off = s1base + (size_t)(nf*16+lq)*256 + ks*32 + quad*8;
      bf16x8 b1 = *(const bf16x8*)(const void*)(S1hi + off);
      acc2[nf] = __builtin_amdgcn_mfma_f32_16x16x32_bf16(qf[ks], b1, acc2[nf], 0,0,0);
      bf16x8 b2 = *(const bf16x8*)(const void*)(S1lo + off);
      acc2[nf] = __builtin_amdgcn_mfma_f32_16x16x32_bf16(qf[ks], b2, acc2[nf], 0,0,0);
    }
  }
  #pragma unroll
  for(int ks=0;ks<2;ks++){
    #pragma unroll
    for(int nf=0;nf<4;nf++){
      size_t off = (gtbase + nf*16+lq)*64 + ks*32 + quad*8;
      bf16x8 gh = *(const bf16x8*)(const void*)(gthi + off);
      bf16x8 gl = *(const bf16x8*)(const void*)(gtlo + off);
      acc2[nf] = __builtin_amdgcn_mfma_f32_16x16x32_bf16(afh[ks], gh, acc2[nf], 0,0,0);
      acc2[nf] = __builtin_amdgcn_mfma_f32_16x16x32_bf16(afh[ks], gl, acc2[nf], 0,0,0);
      acc2[nf] = __builtin_amdgcn_mfma_f32_16x16x32_bf16(afl[ks], gh, acc2[nf], 0,0,0);
    }
  }
  #pragma unroll
  for(int nf=0;nf<4;nf++){
    #pragma unroll
    for(int i=0;i<4;i++){
      int trow = strip + quad*4 + i;
      sc_state[((size_t)bh*T_ + t0 + trow)*64 + nf*16+lq] = acc2[nf][i];
    }
  }
}

// ---------------- fused window attention + o_state, single o write ----------------
// KV loop as round 12 (K reg-prefetch). Tail: p -> P/Pl LDS (no global round-trip),
// g staged+split to LDS, M = tril(p g^T) computed in-kernel, then state MFMAs
// (p@SG + M@V) accumulate into the rescaled o_acc; o stored once.
__global__ __launch_bounds__(256,1) void window_attn_state_mfma(
    const unsigned short* __restrict__ q_bf,
    const unsigned short* __restrict__ k_bf,
    const unsigned short* __restrict__ vt_bf,
    const unsigned short* __restrict__ vtlo_bf,
    const float* __restrict__ sc_state,
    const float* __restrict__ g,
    const unsigned short* __restrict__ S2hi, const unsigned short* __restrict__ S2lo,
    float* __restrict__ o)
{
  int nt=blockIdx.x, h=blockIdx.y, b=blockIdx.z;
  int tid=threadIdx.x;
  int lane = tid & 63, w = tid >> 6;
  int quad = lane >> 4, lq = lane & 15;
  int sp = w >> 1, np = w & 1;
  int t0 = nt*64, bh = b*H_ + h;
  float slope = exp2f(-2.0f*(float)h);

  __shared__ unsigned short kv_lds[256*72];
  __shared__ float S_lds[64*68];
  __shared__ unsigned short P_lds[64*72];
  __shared__ unsigned short Pl_lds[64*72];
  __shared__ unsigned short gh_lds[64*72];
  __shared__ unsigned short gl_lds[64*72];
  __shared__ unsigned short Mh_lds[64*72];
  __shared__ unsigned short Ml_lds[64*72];
  __shared__ float m_lds[64], l_lds[64], al_lds[64];

  bf16x8 qf[2][8];
  #pragma unroll
  for(int st=0; st<2; st++){
    const unsigned short* qrow = q_bf + ((size_t)(b*T_ + t0 + 32*sp + 16*st + lq))*D_ + h*CK_ + quad*8;
    #pragma unroll
    for(int ks=0; ks<8; ks++)
      qf[st][ks] = *(const bf16x8*)(const void*)(qrow + ks*32);
  }

  int jt0 = (nt>=8)? nt-8 : 0;
  int krow = tid>>2, kseg = tid&3;
  bf16x8 kpre[8];
  {
    const unsigned short* src = k_bf + ((size_t)(b*T_ + jt0*64 + krow))*D_ + h*CK_ + kseg*64;
    #pragma unroll
    for(int i=0;i<8;i++) kpre[i] = *(const bf16x8*)(const void*)(src + i*8);
  }

  int r = tid >> 2, part = tid & 3;
  {
    const float* scrow = sc_state + ((size_t)bh*T_ + t0 + r)*64 + part*16;
    float pm = -1e30f, sv[16];
    #pragma unroll
    for(int i=0;i<16;i++){ sv[i] = scrow[i]; pm = fmaxf(pm, sv[i]); }
    pm = fmaxf(pm, __shfl_xor(pm,1)); pm = fmaxf(pm, __shfl_xor(pm,2));
    float ps = 0.f;
    #pragma unroll
    for(int i=0;i<16;i++) ps += __expf(sv[i]-pm);
    ps += __shfl_xor(ps,1); ps += __shfl_xor(ps,2);
    if(part==0){ m_lds[r]=pm; l_lds[r]=ps; }
  }

  f32x4 o_acc[2][8];
  #pragma unroll
  for(int st=0;st<2;st++)
    #pragma unroll
    for(int nv=0;nv<8;nv++) o_acc[st][nv] = (f32x4){0.f,0.f,0.f,0.f};
  __syncthreads();

  for(int jt=jt0; jt<=nt; jt++){
    int j0 = jt*64;
    {
      unsigned short* dst = kv_lds + krow*260 + kseg*64;
      #pragma unroll
      for(int i=0;i<8;i++) *(bf16x8*)(void*)(dst + i*8) = kpre[i];
    }
    __syncthreads();
    if(jt < nt){
      const unsigned short* src = k_bf + ((size_t)(b*T_ + j0 + 64 + krow))*D_ + h*CK_ + kseg*64;
      #pragma unroll
      for(int i=0;i<8;i++) kpre[i] = *(const bf16x8*)(const void*)(src + i*8);
    }
    f32x4 sacc[2][2];
    #pragma unroll
    for(int st=0;st<2;st++)
      #pragma unroll
      for(int n2=0;n2<2;n2++) sacc[st][n2] = (f32x4){0.f,0.f,0.f,0.f};
    #pragma unroll
    for(int n2=0;n2<2;n2++){
      int n = np*2 + n2;
      #pragma unroll
      for(int ks=0;ks<8;ks++){
        bf16x8 kf = *(const bf16x8*)(const void*)(kv_lds + (n*16+lq)*260 + ks*32 + quad*8);
        sacc[0][n2] = __builtin_amdgcn_mfma_f32_16x16x32_bf16(qf[0][ks], kf, sacc[0][n2], 0,0,0);
        sacc[1][n2] = __builtin_amdgcn_mfma_f32_16x16x32_bf16(qf[1][ks], kf, sacc[1][n2], 0,0,0);
      }
    }
    #pragma unroll
    for(int st=0;st<2;st++){
      #pragma unroll
      for(int n2=0;n2<2;n2++){
        int n = np*2+n2;
        int u = j0 + n*16 + lq;
        #pragma unroll
        for(int i=0;i<4;i++){
          int row = 32*sp + 16*st + quad*4 + i;
          int d = (t0 + row) - u;
          float val = (d>=0 && d<W_) ? sacc[st][n2][i] - slope*(float)d : -1e30f;
          S_lds[row*68 + n*16+lq] = val;
        }
      }
    }
    __syncthreads();
    {
      float s16[16], tm = -1e30f;
      #pragma unroll
      for(int i=0;i<16;i++){ s16[i] = S_lds[r*68 + part*16 + i]; tm = fmaxf(tm, s16[i]); }
      tm = fmaxf(tm, __shfl_xor(tm,1)); tm = fmaxf(tm, __shfl_xor(tm,2));
      float m_old = m_lds[r];
      float m_new = fmaxf(m_old, tm);
      float alpha = __expf(m_old - m_new);
      float ts = 0.f;
      union { unsigned short u[16]; bf16x8 v[2]; } pk;
      #pragma unroll
      for(int i=0;i<16;i++){ float p = __expf(s16[i]-m_new); ts += p; pk.u[i] = f2bf(p); }
      ts += __shfl_xor(ts,1); ts += __shfl_xor(ts,2);
      *(bf16x8*)(void*)&P_lds[r*72 + part*16]     = pk.v[0];
      *(bf16x8*)(void*)&P_lds[r*72 + part*16 + 8] = pk.v[1];
      if(part==0){ m_lds[r] = m_new; l_lds[r] = l_lds[r]*alpha + ts; al_lds[r] = alpha; }
      #pragma unroll
      for(int pass=0; pass<4; pass++){
        int cv = (tid>>2) + 64*pass, useg = (tid&3)*16;
        const unsigned short* src = vt_bf + ((size_t)(bh*256 + cv))*T_ + j0 + useg;
        unsigned short* dst = kv_lds + cv*72 + useg;
        *(bf16x8*)(void*)(dst)   = *(const bf16x8*)(const void*)(src);
        *(bf16x8*)(void*)(dst+8) = *(const bf16x8*)(const void*)(src+8);
      }
    }
    __syncthreads();
    #pragma unroll
    for(int st=0;st<2;st++){
      #pragma unroll
      for(int i=0;i<4;i++){
        float al = al_lds[32*sp+16*st+quad*4+i];
        #pragma unroll
        for(int nv=0;nv<8;nv++) o_acc[st][nv][i] *= al;
      }
    }
    bf16x8 pa[2][2];
    #pragma unroll
    for(int st=0;st<2;st++)
      #pragma unroll
      for(int k2=0;k2<2;k2++)
        pa[st][k2] = *(const bf16x8*)(const void*)&P_lds[(32*sp+16*st+lq)*72 + k2*32 + quad*8];
    #pragma unroll
    for(int nv=0;nv<8;nv++){
      int cvt = np*8 + nv;
      #pragma unroll
      for(int k2=0;k2<2;k2++){
        bf16x8 vb = *(const bf16x8*)(const void*)(kv_lds + (cvt*16+lq)*72 + k2*32 + quad*8);
        o_acc[0][nv] = __builtin_amdgcn_mfma_f32_16x16x32_bf16(pa[0][k2], vb, o_acc[0][nv], 0,0,0);
        o_acc[1][nv] = __builtin_amdgcn_mfma_f32_16x16x32_bf16(pa[1][k2], vb, o_acc[1][nv], 0,0,0);
      }
    }
    __syncthreads();
  }

  // ---- tail: rescale o_acc, build p (LDS) and g (LDS), M, state MFMAs ----
  #pragma unroll
  for(int st=0;st<2;st++)
    #pragma unroll
    for(int i=0;i<4;i++){
      int row = 32*sp+16*st+quad*4+i;
      float rl = 1.0f / l_lds[row];
      #pragma unroll
      for(int nv=0;nv<8;nv++) o_acc[st][nv][i] *= rl;
    }
  {
    float mf = m_lds[r], rlf = 1.0f / l_lds[r];
    const float* scrow = sc_state + ((size_t)bh*T_ + t0 + r)*64 + part*16;
    union { unsigned short u[16]; bf16x8 v[2]; } PH, PL;
    #pragma unroll
    for(int i=0;i<16;i++){
      float pv = __expf(scrow[i]-mf)*rlf;
      split2(pv, PH.u[i], PL.u[i]);
    }
    *(bf16x8*)(void*)&P_lds[r*72 + part*16]      = PH.v[0];
    *(bf16x8*)(void*)&P_lds[r*72 + part*16 + 8]  = PH.v[1];
    *(bf16x8*)(void*)&Pl_lds[r*72 + part*16]     = PL.v[0];
    *(bf16x8*)(void*)&Pl_lds[r*72 + part*16 + 8] = PL.v[1];
  }
  {
    int gu = tid>>2, gs0 = (tid&3)*16;
    const float* gr = g + ((size_t)(b*T_+t0+gu))*256 + h*64 + gs0;
    union{ unsigned short u[16]; bf16x8 v[2]; } GH, GL;
    #pragma unroll
    for(int j=0;j<16;j++) split2(gr[j], GH.u[j], GL.u[j]);
    *(bf16x8*)(void*)&gh_lds[gu*72+gs0]   = GH.v[0];
    *(bf16x8*)(void*)&gh_lds[gu*72+gs0+8] = GH.v[1];
    *(bf16x8*)(void*)&gl_lds[gu*72+gs0]   = GL.v[0];
    *(bf16x8*)(void*)&gl_lds[gu*72+gs0+8] = GL.v[1];
  }
  __syncthreads();

  // M strip: wave w owns rows w*16..+16
  {
    int strip = w*16;
    f32x4 ma[4];
    #pragma unroll
    for(int nf=0;nf<4;nf++) ma[nf] = (f32x4){0.f,0.f,0.f,0.f};
    #pragma unroll
    for(int ks=0;ks<2;ks++){
      bf16x8 pfh = *(const bf16x8*)(const void*)&P_lds[(strip+lq)*72 + ks*32 + quad*8];
      bf16x8 pfl = *(const bf16x8*)(const void*)&Pl_lds[(strip+lq)*72 + ks*32 + quad*8];
      #pragma unroll
      for(int nf=0;nf<4;nf++){
        bf16x8 gH = *(const bf16x8*)(const void*)&gh_lds[(nf*16+lq)*72 + ks*32 + quad*8];
        bf16x8 gL = *(const bf16x8*)(const void*)&gl_lds[(nf*16+lq)*72 + ks*32 + quad*8];
        ma[nf] = __builtin_amdgcn_mfma_f32_16x16x32_bf16(pfh, gH, ma[nf], 0,0,0);
        ma[nf] = __builtin_amdgcn_mfma_f32_16x16x32_bf16(pfh, gL, ma[nf], 0,0,0);
        ma[nf] = __builtin_amdgcn_mfma_f32_16x16x32_bf16(pfl, gH, ma[nf], 0,0,0);
      }
    }
    #pragma unroll
    for(int nf=0;nf<4;nf++){
      int u = nf*16 + lq;
      #pragma unroll
      for(int i=0;i<4;i++){
        int trow = strip + quad*4 + i;
        float val = (u <= trow) ? ma[nf][i] : 0.f;
        unsigned short hh, ll;
        split2(val, hh, ll);
        Mh_lds[trow*72 + u] = hh;
        Ml_lds[trow*72 + u] = ll;
      }
    }
  }
  __syncthreads();

  // state MFMAs accumulate into o_acc: rows 32sp+16st, cols (np*8+nv)*16+lq
  size_t sgbase = ((size_t)bh*NC_ + nt)*16384;
  #pragma unroll
  for(int ks=0;ks<2;ks++){
    bf16x8 pAh[2], pAl[2], mAh[2], mAl[2];
    #pragma unroll
    for(int st=0;st<2;st++){
      int rowb = (32*sp + 16*st + lq)*72 + ks*32 + quad*8;
      pAh[st] = *(const bf16x8*)(const void*)&P_lds[rowb];
      pAl[st] = *(const bf16x8*)(const void*)&Pl_lds[rowb];
      mAh[st] = *(const bf16x8*)(const void*)&Mh_lds[rowb];
      mAl[st] = *(const bf16x8*)(const void*)&Ml_lds[rowb];
    }
    #pragma unroll
    for(int nv=0;nv<8;nv++){
      int c = (np*8+nv)*16 + lq;
      size_t so = sgbase + (size_t)c*64 + ks*32 + quad*8;
      bf16x8 sgH = *(const bf16x8*)(const void*)(S2hi + so);
      bf16x8 sgL = *(const bf16x8*)(const void*)(S2lo + so);
      size_t vo = ((size_t)(bh*256 + c))*T_ + t0 + ks*32 + quad*8;
      bf16x8 vH = *(const bf16x8*)(const void*)(vt_bf + vo);
      bf16x8 vL = *(const bf16x8*)(const void*)(vtlo_bf + vo);
      #pragma unroll
      for(int st=0;st<2;st++){
        o_acc[st][nv] = __builtin_amdgcn_mfma_f32_16x16x32_bf16(pAh[st], sgH, o_acc[st][nv], 0,0,0);
        o_acc[st][nv] = __builtin_amdgcn_mfma_f32_16x16x32_bf16(pAh[st], sgL, o_acc[st][nv], 0,0,0);
        o_acc[st][nv] = __builtin_amdgcn_mfma_f32_16x16x32_bf16(pAl[st], sgH, o_acc[st][nv], 0,0,0);
        o_acc[st][nv] = __builtin_amdgcn_mfma_f32_16x16x32_bf16(mAh[st], vH, o_acc[st][nv], 0,0,0);
        o_acc[st][nv] = __builtin_amdgcn_mfma_f32_16x16x32_bf16(mAl[st], vH, o_acc[st][nv], 0,0,0);
        o_acc[st][nv] = __builtin_amdgcn_mfma_f32_16x16x32_bf16(mAh[st], vL, o_acc[st][nv], 0,0,0);
      }
    }
  }
  #pragma unroll
  for(int st=0;st<2;st++){
    #pragma unroll
    for(int i=0;i<4;i++){
      int row = 32*sp+16*st+quad*4+i;
      #pragma unroll
      for(int nv=0;nv<8;nv++){
        int cv = (np*8+nv)*16 + lq;
        o[((size_t)bh*T_ + t0 + row)*256 + cv] = o_acc[st][nv][i];
      }
    }
  }
}

// ---------------- swish + rmsnorm, gather heads -> split bf16 hi/lo ----------------
__global__ void swish_rms_split_kernel(const float* __restrict__ o, const float* __restrict__ w,
                                       unsigned short* __restrict__ ohi, unsigned short* __restrict__ olo){
  int bt=blockIdx.x, tid=threadIdx.x;
  int b = bt >> 11, t = bt & 2047;
  float y[4]; float ss=0.f;
  #pragma unroll
  for(int hh=0;hh<4;hh++){
    float x = o[((size_t)(b*H_+hh)*T_ + t)*256 + tid];
    float yy = x / (1.f + expf(-x));
    y[hh]=yy; ss += yy*yy;
  }
  __shared__ float red[256];
  red[tid]=ss; __syncthreads();
  for(int s2=128;s2>0;s2>>=1){ if(tid<s2) red[tid]+=red[tid+s2]; __syncthreads(); }
  float r = rsqrtf(red[0]/1024.f + 1e-5f);
  #pragma unroll
  for(int hh=0;hh<4;hh++){
    unsigned short a,bq;
    split2(y[hh]*r*w[hh*256+tid], a, bq);
    ohi[(size_t)bt*1024 + hh*256 + tid] = a;
    olo[(size_t)bt*1024 + hh*256 + tid] = bq;
  }
}

extern "C" void kernel_launch(void* const* d_in, const int* in_sizes, int n_in,
                              void* d_out, int out_size, void* d_ws, size_t ws_size,
                              hipStream_t stream){
  const float* hidden = (const float*)d_in[0];
  const float* w_norm = (const float*)d_in[1];
  const float* Wq = (const float*)d_in[2];
  const float* Wk = (const float*)d_in[3];
  const float* Wv = (const float*)d_in[4];
  const float* Ws = (const float*)d_in[5];
  const float* Wg = (const float*)d_in[6];
  const float* Wo = (const float*)d_in[7];
  float* out = (float*)d_out;

  char* p = (char*)d_ws;
  auto alloc = [&](size_t bytes)->void*{ void* r = (void*)p; p += (bytes + 255) & ~(size_t)255; return r; };
  unsigned short* h_hi = (unsigned short*)alloc(8388608);   // (4096,1024) bf16; P2f mid; o2_hi late
  unsigned short* h_lo = (unsigned short*)alloc(8388608);   //               ; o2_lo late
  unsigned short* Wc_hi = (unsigned short*)alloc(11010048); // (5376,1024) bf16 [Wq;Wk;Ws;Wv;Wg;Wo]
  unsigned short* Wc_lo = (unsigned short*)alloc(11010048);
  unsigned short* vslot = (unsigned short*)alloc(16777216); // vtlo (8.39MB) + S2hi (8.39MB)
  float* g   = (float*)alloc(4194304);                      // (4096,256) f32 — alive until window_attn
  float* P1  = (float*)alloc(16777216);                     // G^T@S chunks; o aliases after prefix_split
  float* P2  = (float*)alloc(16777216);                     // S1hi/S1lo
  float* sc  = (float*)alloc(4194304);                      // (8,2048,64)
  float* ps  = (float*)alloc(4194304);                      // GThi/GTlo
  unsigned short* qks = (unsigned short*)alloc(25165824);   // q|k|s bf16, 3x(4096,1024)
  unsigned short* vt  = (unsigned short*)alloc(8388608);    // V^T bf16 hi (8,256,2048)

  unsigned short* vtlo = vslot;                    // V^T bf16 lo
  unsigned short* S2hi = vslot + 4194304;          // SG prefix hi (c-major chunks)
  unsigned short* q_bf = qks;
  unsigned short* k_bf = qks + 4194304;
  unsigned short* s_bf = qks + 8388608;
  unsigned short* S2lo = s_bf;                     // s_bf dead after sc_state; S2lo born after
  float* o = P1;                                   // P1 dead after chunk_prefix_split
  float* P2f = (float*)h_hi;                       // G^T@V f32 (16MB, h region dead after gemm0)
  unsigned short* S1hi = (unsigned short*)P2;
  unsigned short* S1lo = S1hi + 4194304;
  unsigned short* GThi = (unsigned short*)ps;
  unsigned short* GTlo = GThi + 1048576;

  norm_wsplit_kernel<<<9472,256,0,stream>>>(hidden, w_norm, h_hi, h_lo,
                                            Wq, Wk, Ws, Wv, Wg, Wo, Wc_hi, Wc_lo);
  gemm_bf16s<<<dim3(34,32),256,0,stream>>>(h_hi, h_lo, Wc_hi, Wc_lo,
                                           qks, vt, vtlo, g, nullptr, 0);
  softmax256_gt_kernel<<<4096,256,0,stream>>>(g, GThi, GTlo);
  dim3 gc(32,4,2);
  chunk_outer_both<<<gc,256,0,stream>>>(GThi, GTlo, s_bf, vt, vtlo, P1, P2f);
  chunk_prefix_split_kernel<<<512,256,0,stream>>>(P1, S1hi, S1lo);
  sc_state_mfma<<<gc,256,0,stream>>>(q_bf, s_bf, S1hi, S1lo, GThi, GTlo, sc);
  chunk_prefix_split_kernel<<<512,256,0,stream>>>(P2f, S2hi, S2lo);
  window_attn_state_mfma<<<gc,256,0,stream>>>(q_bf, k_bf, vt, vtlo, sc, g, S2hi, S2lo, o);
  swish_rms_split_kernel<<<4096,256,0,stream>>>(o, w_norm, h_hi, h_lo);
  gemm_bf16s<<<dim3(8,32),256,0,stream>>>(h_hi, h_lo, Wc_hi + (size_t)4352*1024, Wc_lo + (size_t)4352*1024,
                                          nullptr, nullptr, nullptr, nullptr, out, 1);
}